// Round 4
// baseline (1050.938 us; speedup 1.0000x reference)
//
#include <hip/hip_runtime.h>
#include <math.h>

#define BB_  1024
#define NN_  256
#define MM_  128
#define PP_  64
#define KKc  128   // N - M

// ---------------------------------------------------------------------------
// k_pre2: QfQn = Qf@Qn (256x128) | WfQn[c][r] = sum_n Wf[n][c]Qn[n][r] (64x128)
//         bb = parms@Bp.T (1024x128) | QrT[m][n] = Qr[n][m] | QnT[r][n]=Qn[n][r]
// ---------------------------------------------------------------------------
__global__ __launch_bounds__(256) void k_pre2(
    const float* __restrict__ Qf, const float* __restrict__ Qn,
    const float* __restrict__ Wf, const float* __restrict__ parms,
    const float* __restrict__ Bp, const float* __restrict__ Qr,
    float* __restrict__ QfQn, float* __restrict__ WfQn,
    float* __restrict__ bb, float* __restrict__ QrT, float* __restrict__ QnT)
{
  const int w = blockIdx.x, tid = threadIdx.x;
  if (w < 128) {
    __shared__ float arow[2][NN_];
    const int n0 = 2 * w;
    for (int idx = tid; idx < 2 * NN_; idx += 256)
      arow[idx >> 8][idx & 255] = Qf[(n0 + (idx >> 8)) * NN_ + (idx & 255)];
    __syncthreads();
    const int r = tid & 127, h = tid >> 7;
    float acc = 0.f;
    for (int m = 0; m < NN_; ++m) acc += arow[h][m] * Qn[m * KKc + r];
    QfQn[(n0 + h) * KKc + r] = acc;
  } else if (w < 160) {
    __shared__ float wcol[2][NN_];
    const int c0 = 2 * (w - 128);
    for (int idx = tid; idx < 2 * NN_; idx += 256)
      wcol[idx >> 8][idx & 255] = Wf[(idx & 255) * PP_ + c0 + (idx >> 8)];
    __syncthreads();
    const int r = tid & 127, h = tid >> 7;
    float acc = 0.f;
    for (int n = 0; n < NN_; ++n) acc += wcol[h][n] * Qn[n * KKc + r];
    WfQn[(c0 + h) * KKc + r] = acc;
  } else if (w < 672) {
    __shared__ float BpP[MM_ * 65];
    __shared__ float pr[2][PP_];
    const int b0 = 2 * (w - 160);
    for (int idx = tid; idx < MM_ * PP_; idx += 256) {
      int m = idx >> 6, p = idx & 63;
      BpP[m * 65 + p] = Bp[idx];
    }
    for (int idx = tid; idx < 2 * PP_; idx += 256)
      pr[idx >> 6][idx & 63] = parms[(b0 + (idx >> 6)) * PP_ + (idx & 63)];
    __syncthreads();
    const int m = tid & 127, h = tid >> 7;
    float acc = 0.f;
    for (int p = 0; p < PP_; ++p) acc += pr[h][p] * BpP[m * 65 + p];
    bb[(b0 + h) * MM_ + m] = acc;
  } else if (w < 800) {
    const int mm = w - 672;
    QrT[mm * NN_ + tid] = Qr[tid * MM_ + mm];
  } else {
    // QnT: 32768 elements over 32 wgs, 4 per thread
    const int idx = (w - 800) * 1024 + tid * 4;
    const int r = idx >> 8, n = idx & 255;
    float4 v;
    v.x = Qn[(n + 0) * KKc + r];
    v.y = Qn[(n + 1) * KKc + r];
    v.z = Qn[(n + 2) * KKc + r];
    v.w = Qn[(n + 3) * KKc + r];
    *reinterpret_cast<float4*>(&QnT[idx]) = v;
  }
}

// ---------------------------------------------------------------------------
// k_pre3: C = Qn.T @ QfQn (128x128)  |  batched forward-sub: bb <- zeta_r
// ---------------------------------------------------------------------------
__global__ __launch_bounds__(256) void k_pre3(
    const float* __restrict__ Qn, const float* __restrict__ QfQn,
    const float* __restrict__ Rr, float* __restrict__ C, float* __restrict__ bb)
{
  const int w = blockIdx.x, tid = threadIdx.x;
  if (w < 64) {
    __shared__ float qcol[2][NN_];
    const int r0 = 2 * w;
    for (int idx = tid; idx < 2 * NN_; idx += 256)
      qcol[idx >> 8][idx & 255] = Qn[(idx & 255) * KKc + r0 + (idx >> 8)];
    __syncthreads();
    const int s = tid & 127, h = tid >> 7;
    float acc = 0.f;
    for (int n = 0; n < NN_; ++n) acc += qcol[h][n] * QfQn[n * KKc + s];
    C[(r0 + h) * KKc + s] = acc;
  } else {
    __shared__ float Wt[MM_ * 65];
    const int b0 = (w - 64) * 64;
    for (int idx = tid; idx < 64 * MM_; idx += 256) {
      int b = idx >> 7, m = idx & 127;
      Wt[m * 65 + b] = bb[(b0 + b) * MM_ + m];
    }
    __syncthreads();
    const int c = tid & 63, q = tid >> 6;
    if (q == 0) Wt[0 * 65 + c] /= Rr[0];
    for (int i = 0; i < MM_; ++i) {
      __syncthreads();
      float xi = Wt[i * 65 + c];
      for (int k = i + 1 + q; k < MM_; k += 4) {
        float v = Wt[k * 65 + c] - Rr[i * MM_ + k] * xi;
        if (k == i + 1) v /= Rr[k * MM_ + k];
        Wt[k * 65 + c] = v;
      }
    }
    __syncthreads();
    for (int idx = tid; idx < 64 * MM_; idx += 256) {
      int b = idx >> 7, m = idx & 127;
      bb[(b0 + b) * MM_ + m] = Wt[m * 65 + b];
    }
  }
}

// ---------------------------------------------------------------------------
// k_vec: per batch: zeta = zeta_r @ Qr.T  -> written into OUT (reused later)
//        t = (1+x^2)(x - zeta); rhs = t@Qn - zeta@QfQn - parms@WfQn
// ---------------------------------------------------------------------------
__global__ __launch_bounds__(256) void k_vec(
    const float* __restrict__ x, const float* __restrict__ parms,
    const float* __restrict__ zr, const float* __restrict__ QrT,
    const float* __restrict__ Qn, const float* __restrict__ QfQn,
    const float* __restrict__ WfQn,
    float* __restrict__ out_zeta, float* __restrict__ rhs)
{
  const int b0 = blockIdx.x * 2, tid = threadIdx.x;
  __shared__ float zrL[2][MM_], pL[2][PP_], xL[2][NN_], zL[2][NN_], tL[2][NN_];
  for (int idx = tid; idx < 2 * MM_; idx += 256)
    zrL[idx >> 7][idx & 127] = zr[(b0 + (idx >> 7)) * MM_ + (idx & 127)];
  for (int idx = tid; idx < 2 * PP_; idx += 256)
    pL[idx >> 6][idx & 63] = parms[(b0 + (idx >> 6)) * PP_ + (idx & 63)];
  for (int idx = tid; idx < 2 * NN_; idx += 256)
    xL[idx >> 8][idx & 255] = x[(b0 + (idx >> 8)) * NN_ + (idx & 255)];
  __syncthreads();
  {
    const int n = tid;
    float a0 = 0.f, a1 = 0.f;
    for (int m = 0; m < MM_; ++m) {
      float qv = QrT[m * NN_ + n];
      a0 += zrL[0][m] * qv;
      a1 += zrL[1][m] * qv;
    }
    float x0 = xL[0][n], x1 = xL[1][n];
    zL[0][n] = a0; zL[1][n] = a1;
    float t0 = (1.f + x0 * x0) * (x0 - a0);
    float t1 = (1.f + x1 * x1) * (x1 - a1);
    tL[0][n] = t0; tL[1][n] = t1;
    out_zeta[b0 * NN_ + n] = a0;
    out_zeta[(b0 + 1) * NN_ + n] = a1;
  }
  __syncthreads();
  {
    const int r = tid & 127, h = tid >> 7;
    float acc = 0.f;
    for (int n = 0; n < NN_; ++n) acc += tL[h][n] * Qn[n * KKc + r];
    for (int n = 0; n < NN_; ++n) acc -= zL[h][n] * QfQn[n * KKc + r];
    for (int c = 0; c < PP_; ++c) acc -= pL[h][c] * WfQn[c * KKc + r];
    rhs[(b0 + h) * KKc + r] = acc;
  }
}

// ---------------------------------------------------------------------------
// k_cg: batched CG on S z = rhs, S = C + Qn^T diag(1+x^2) Qn (never formed).
// One wg = 4 batches; wave b owns batch b. Thread (b, q=lane):
//   GEMV1 rows n = 4q..4q+3 (streams Qn rows),  w = d .* (Qn p)  -> LDS
//   GEMV2 rows r = 2q, 2q+1 (streams QnT + C rows), v = QnT w + C p
//   dots: single-wave shfl butterflies; rs recomputed directly (no recurrence)
// Epilogue: out = zeta(read from out) + Qn z.
// ---------------------------------------------------------------------------
__global__ __launch_bounds__(256) void k_cg(
    const float* __restrict__ x, const float* __restrict__ Qn,
    const float* __restrict__ QnT, const float* __restrict__ C,
    const float* __restrict__ rhs, float* __restrict__ out)
{
  const int b = threadIdx.x >> 6;     // wave id = batch lane (0..3)
  const int q = threadIdx.x & 63;
  const int batch = blockIdx.x * 4 + b;

  __shared__ __align__(16) float p_lds[2][4][KKc];
  __shared__ __align__(16) float w_lds[4][NN_];
  __shared__ __align__(16) float z_lds[4][KKc];

  // d for this thread's 4 GEMV1 rows (n = 4q+j)
  float4 xv = *reinterpret_cast<const float4*>(&x[batch * NN_ + 4 * q]);
  const float d0 = 1.f + xv.x * xv.x, d1 = 1.f + xv.y * xv.y,
              d2 = 1.f + xv.z * xv.z, d3 = 1.f + xv.w * xv.w;

  // CG state for r-pair (2q, 2q+1)
  float2 r2 = *reinterpret_cast<const float2*>(&rhs[batch * KKc + 2 * q]);
  float rr0 = r2.x, rr1 = r2.y;
  float z0 = 0.f, z1 = 0.f, p0 = rr0, p1 = rr1;

  float rs = rr0 * rr0 + rr1 * rr1;
#pragma unroll
  for (int m = 32; m; m >>= 1) rs += __shfl_xor(rs, m, 64);

  p_lds[0][b][2 * q] = p0; p_lds[0][b][2 * q + 1] = p1;

  const float4* qn0 = reinterpret_cast<const float4*>(&Qn[(4 * q + 0) * KKc]);
  const float4* qn1 = reinterpret_cast<const float4*>(&Qn[(4 * q + 1) * KKc]);
  const float4* qn2 = reinterpret_cast<const float4*>(&Qn[(4 * q + 2) * KKc]);
  const float4* qn3 = reinterpret_cast<const float4*>(&Qn[(4 * q + 3) * KKc]);
  const float4* qt0 = reinterpret_cast<const float4*>(&QnT[(2 * q + 0) * NN_]);
  const float4* qt1 = reinterpret_cast<const float4*>(&QnT[(2 * q + 1) * NN_]);
  const float4* cr0 = reinterpret_cast<const float4*>(&C[(2 * q + 0) * KKc]);
  const float4* cr1 = reinterpret_cast<const float4*>(&C[(2 * q + 1) * KKc]);
  const float4* wb  = reinterpret_cast<const float4*>(w_lds[b]);

  __syncthreads();

  int cur = 0;
  for (int it = 0; it < 18; ++it) {
    const float4* pb = reinterpret_cast<const float4*>(p_lds[cur][b]);

    // ---- GEMV1: u = Qn p (4 rows), w = d .* u ----
    float u0 = 0.f, u1 = 0.f, u2 = 0.f, u3 = 0.f;
#pragma unroll 8
    for (int c = 0; c < 32; ++c) {
      float4 pp = pb[c];
      float4 a0 = qn0[c], a1 = qn1[c], a2 = qn2[c], a3 = qn3[c];
      u0 += a0.x * pp.x + a0.y * pp.y + a0.z * pp.z + a0.w * pp.w;
      u1 += a1.x * pp.x + a1.y * pp.y + a1.z * pp.z + a1.w * pp.w;
      u2 += a2.x * pp.x + a2.y * pp.y + a2.z * pp.z + a2.w * pp.w;
      u3 += a3.x * pp.x + a3.y * pp.y + a3.z * pp.z + a3.w * pp.w;
    }
    float4 wv = {u0 * d0, u1 * d1, u2 * d2, u3 * d3};
    *reinterpret_cast<float4*>(&w_lds[b][4 * q]) = wv;
    __syncthreads();

    // ---- GEMV2: v = QnT w + C p (2 rows) ----
    float v0 = 0.f, v1 = 0.f;
#pragma unroll 8
    for (int c = 0; c < 64; ++c) {
      float4 ww = wb[c];
      float4 t0 = qt0[c], t1 = qt1[c];
      v0 += t0.x * ww.x + t0.y * ww.y + t0.z * ww.z + t0.w * ww.w;
      v1 += t1.x * ww.x + t1.y * ww.y + t1.z * ww.z + t1.w * ww.w;
    }
#pragma unroll 8
    for (int c = 0; c < 32; ++c) {
      float4 pp = pb[c];
      float4 c0 = cr0[c], c1 = cr1[c];
      v0 += c0.x * pp.x + c0.y * pp.y + c0.z * pp.z + c0.w * pp.w;
      v1 += c1.x * pp.x + c1.y * pp.y + c1.z * pp.z + c1.w * pp.w;
    }

    // ---- alpha = rs / (p.v) ----
    float pv = p0 * v0 + p1 * v1;
#pragma unroll
    for (int m = 32; m; m >>= 1) pv += __shfl_xor(pv, m, 64);
    float alpha = rs / (pv + 1e-30f);
    z0 += alpha * p0;  z1 += alpha * p1;
    rr0 -= alpha * v0; rr1 -= alpha * v1;

    // ---- rs_new = r.r (direct, no recurrence) ----
    float rsn = rr0 * rr0 + rr1 * rr1;
#pragma unroll
    for (int m = 32; m; m >>= 1) rsn += __shfl_xor(rsn, m, 64);
    float beta = rsn / (rs + 1e-30f);
    rs = rsn;
    p0 = rr0 + beta * p0; p1 = rr1 + beta * p1;

    p_lds[cur ^ 1][b][2 * q] = p0;
    p_lds[cur ^ 1][b][2 * q + 1] = p1;
    __syncthreads();
    cur ^= 1;
  }

  // ---- epilogue: out = zeta(in out) + Qn z ----
  z_lds[b][2 * q] = z0; z_lds[b][2 * q + 1] = z1;
  __syncthreads();
  float4 o = *reinterpret_cast<const float4*>(&out[batch * NN_ + 4 * q]);
  const float4* zb = reinterpret_cast<const float4*>(z_lds[b]);
#pragma unroll 8
  for (int c = 0; c < 32; ++c) {
    float4 zz = zb[c];
    float4 a0 = qn0[c], a1 = qn1[c], a2 = qn2[c], a3 = qn3[c];
    o.x += a0.x * zz.x + a0.y * zz.y + a0.z * zz.z + a0.w * zz.w;
    o.y += a1.x * zz.x + a1.y * zz.y + a1.z * zz.z + a1.w * zz.w;
    o.z += a2.x * zz.x + a2.y * zz.y + a2.z * zz.z + a2.w * zz.w;
    o.w += a3.x * zz.x + a3.y * zz.y + a3.z * zz.z + a3.w * zz.w;
  }
  *reinterpret_cast<float4*>(&out[batch * NN_ + 4 * q]) = o;
}

// ---------------------------------------------------------------------------
extern "C" void kernel_launch(void* const* d_in, const int* in_sizes, int n_in,
                              void* d_out, int out_size, void* d_ws, size_t ws_size,
                              hipStream_t stream)
{
  const float* x     = (const float*)d_in[0];
  const float* parms = (const float*)d_in[1];
  // d_in[2] = A : unused (cancels algebraically)
  const float* Bp    = (const float*)d_in[3];
  const float* Qf    = (const float*)d_in[4];
  const float* Wf    = (const float*)d_in[5];
  const float* Qr    = (const float*)d_in[6];
  const float* Qn    = (const float*)d_in[7];
  const float* Rr    = (const float*)d_in[8];

  // Compact workspace: 385,024 floats = 1.47 MB (Round-2-proven: 2.46 MB).
  // zeta lives in d_out (k_vec writes it, k_cg reads + overwrites in place).
  float* ws   = (float*)d_ws;
  float* QfQn = ws;                 // [0      , 32768)
  float* WfQn = QfQn + 32768;       // [32768  , 40960)
  float* bb   = WfQn + 8192;        // [40960  , 172032)  bb -> zeta_r in place
  float* QrT  = bb + 131072;        // [172032 , 204800)
  float* Cm   = QrT + 32768;        // [204800 , 221184)
  float* QnT  = Cm + 16384;         // [221184 , 253952)
  float* rhs  = QnT + 32768;        // [253952 , 385024)

  float* outp = (float*)d_out;

  hipLaunchKernelGGL(k_pre2, dim3(832), dim3(256), 0, stream,
                     Qf, Qn, Wf, parms, Bp, Qr, QfQn, WfQn, bb, QrT, QnT);
  hipLaunchKernelGGL(k_pre3, dim3(80), dim3(256), 0, stream,
                     Qn, QfQn, Rr, Cm, bb);
  hipLaunchKernelGGL(k_vec, dim3(512), dim3(256), 0, stream,
                     x, parms, bb, QrT, Qn, QfQn, WfQn, outp, rhs);
  hipLaunchKernelGGL(k_cg, dim3(256), dim3(256), 0, stream,
                     x, Qn, QnT, Cm, rhs, outp);
}

// Round 5
// 687.343 us; speedup vs baseline: 1.5290x; 1.5290x over previous
//
#include <hip/hip_runtime.h>
#include <math.h>

#define BB_  1024
#define NN_  256
#define MM_  128
#define PP_  64
#define KKc  128   // N - M

// ---------------------------------------------------------------------------
// k_pre2: QfQn = Qf@Qn (256x128) | WfQn[c][r] = sum_n Wf[n][c]Qn[n][r] (64x128)
//         bb = parms@Bp.T (1024x128) | QrT[m][n] = Qr[n][m] | QnT[r][n]=Qn[n][r]
// ---------------------------------------------------------------------------
__global__ __launch_bounds__(256) void k_pre2(
    const float* __restrict__ Qf, const float* __restrict__ Qn,
    const float* __restrict__ Wf, const float* __restrict__ parms,
    const float* __restrict__ Bp, const float* __restrict__ Qr,
    float* __restrict__ QfQn, float* __restrict__ WfQn,
    float* __restrict__ bb, float* __restrict__ QrT, float* __restrict__ QnT)
{
  const int w = blockIdx.x, tid = threadIdx.x;
  if (w < 128) {
    __shared__ float arow[2][NN_];
    const int n0 = 2 * w;
    for (int idx = tid; idx < 2 * NN_; idx += 256)
      arow[idx >> 8][idx & 255] = Qf[(n0 + (idx >> 8)) * NN_ + (idx & 255)];
    __syncthreads();
    const int r = tid & 127, h = tid >> 7;
    float acc = 0.f;
    for (int m = 0; m < NN_; ++m) acc += arow[h][m] * Qn[m * KKc + r];
    QfQn[(n0 + h) * KKc + r] = acc;
  } else if (w < 160) {
    __shared__ float wcol[2][NN_];
    const int c0 = 2 * (w - 128);
    for (int idx = tid; idx < 2 * NN_; idx += 256)
      wcol[idx >> 8][idx & 255] = Wf[(idx & 255) * PP_ + c0 + (idx >> 8)];
    __syncthreads();
    const int r = tid & 127, h = tid >> 7;
    float acc = 0.f;
    for (int n = 0; n < NN_; ++n) acc += wcol[h][n] * Qn[n * KKc + r];
    WfQn[(c0 + h) * KKc + r] = acc;
  } else if (w < 672) {
    __shared__ float BpP[MM_ * 65];
    __shared__ float pr[2][PP_];
    const int b0 = 2 * (w - 160);
    for (int idx = tid; idx < MM_ * PP_; idx += 256) {
      int m = idx >> 6, p = idx & 63;
      BpP[m * 65 + p] = Bp[idx];
    }
    for (int idx = tid; idx < 2 * PP_; idx += 256)
      pr[idx >> 6][idx & 63] = parms[(b0 + (idx >> 6)) * PP_ + (idx & 63)];
    __syncthreads();
    const int m = tid & 127, h = tid >> 7;
    float acc = 0.f;
    for (int p = 0; p < PP_; ++p) acc += pr[h][p] * BpP[m * 65 + p];
    bb[(b0 + h) * MM_ + m] = acc;
  } else if (w < 800) {
    const int mm = w - 672;
    QrT[mm * NN_ + tid] = Qr[tid * MM_ + mm];
  } else {
    // QnT: 32768 elements over 32 wgs, 4 per thread
    const int idx = (w - 800) * 1024 + tid * 4;
    const int r = idx >> 8, n = idx & 255;
    float4 v;
    v.x = Qn[(n + 0) * KKc + r];
    v.y = Qn[(n + 1) * KKc + r];
    v.z = Qn[(n + 2) * KKc + r];
    v.w = Qn[(n + 3) * KKc + r];
    *reinterpret_cast<float4*>(&QnT[idx]) = v;
  }
}

// ---------------------------------------------------------------------------
// k_pre3: C = Qn.T @ QfQn (128x128)  |  batched forward-sub: bb <- zeta_r
// ---------------------------------------------------------------------------
__global__ __launch_bounds__(256) void k_pre3(
    const float* __restrict__ Qn, const float* __restrict__ QfQn,
    const float* __restrict__ Rr, float* __restrict__ C, float* __restrict__ bb)
{
  const int w = blockIdx.x, tid = threadIdx.x;
  if (w < 64) {
    __shared__ float qcol[2][NN_];
    const int r0 = 2 * w;
    for (int idx = tid; idx < 2 * NN_; idx += 256)
      qcol[idx >> 8][idx & 255] = Qn[(idx & 255) * KKc + r0 + (idx >> 8)];
    __syncthreads();
    const int s = tid & 127, h = tid >> 7;
    float acc = 0.f;
    for (int n = 0; n < NN_; ++n) acc += qcol[h][n] * QfQn[n * KKc + s];
    C[(r0 + h) * KKc + s] = acc;
  } else {
    __shared__ float Wt[MM_ * 65];
    const int b0 = (w - 64) * 64;
    for (int idx = tid; idx < 64 * MM_; idx += 256) {
      int b = idx >> 7, m = idx & 127;
      Wt[m * 65 + b] = bb[(b0 + b) * MM_ + m];
    }
    __syncthreads();
    const int c = tid & 63, q = tid >> 6;
    if (q == 0) Wt[0 * 65 + c] /= Rr[0];
    for (int i = 0; i < MM_; ++i) {
      __syncthreads();
      float xi = Wt[i * 65 + c];
      for (int k = i + 1 + q; k < MM_; k += 4) {
        float v = Wt[k * 65 + c] - Rr[i * MM_ + k] * xi;
        if (k == i + 1) v /= Rr[k * MM_ + k];
        Wt[k * 65 + c] = v;
      }
    }
    __syncthreads();
    for (int idx = tid; idx < 64 * MM_; idx += 256) {
      int b = idx >> 7, m = idx & 127;
      bb[(b0 + b) * MM_ + m] = Wt[m * 65 + b];
    }
  }
}

// ---------------------------------------------------------------------------
// k_vec: per batch: zeta = zeta_r @ Qr.T  -> written into OUT (reused later)
//        t = (1+x^2)(x - zeta); rhs = t@Qn - zeta@QfQn - parms@WfQn
// ---------------------------------------------------------------------------
__global__ __launch_bounds__(256) void k_vec(
    const float* __restrict__ x, const float* __restrict__ parms,
    const float* __restrict__ zr, const float* __restrict__ QrT,
    const float* __restrict__ Qn, const float* __restrict__ QfQn,
    const float* __restrict__ WfQn,
    float* __restrict__ out_zeta, float* __restrict__ rhs)
{
  const int b0 = blockIdx.x * 2, tid = threadIdx.x;
  __shared__ float zrL[2][MM_], pL[2][PP_], xL[2][NN_], zL[2][NN_], tL[2][NN_];
  for (int idx = tid; idx < 2 * MM_; idx += 256)
    zrL[idx >> 7][idx & 127] = zr[(b0 + (idx >> 7)) * MM_ + (idx & 127)];
  for (int idx = tid; idx < 2 * PP_; idx += 256)
    pL[idx >> 6][idx & 63] = parms[(b0 + (idx >> 6)) * PP_ + (idx & 63)];
  for (int idx = tid; idx < 2 * NN_; idx += 256)
    xL[idx >> 8][idx & 255] = x[(b0 + (idx >> 8)) * NN_ + (idx & 255)];
  __syncthreads();
  {
    const int n = tid;
    float a0 = 0.f, a1 = 0.f;
    for (int m = 0; m < MM_; ++m) {
      float qv = QrT[m * NN_ + n];
      a0 += zrL[0][m] * qv;
      a1 += zrL[1][m] * qv;
    }
    float x0 = xL[0][n], x1 = xL[1][n];
    zL[0][n] = a0; zL[1][n] = a1;
    float t0 = (1.f + x0 * x0) * (x0 - a0);
    float t1 = (1.f + x1 * x1) * (x1 - a1);
    tL[0][n] = t0; tL[1][n] = t1;
    out_zeta[b0 * NN_ + n] = a0;
    out_zeta[(b0 + 1) * NN_ + n] = a1;
  }
  __syncthreads();
  {
    const int r = tid & 127, h = tid >> 7;
    float acc = 0.f;
    for (int n = 0; n < NN_; ++n) acc += tL[h][n] * Qn[n * KKc + r];
    for (int n = 0; n < NN_; ++n) acc -= zL[h][n] * QfQn[n * KKc + r];
    for (int c = 0; c < PP_; ++c) acc -= pL[h][c] * WfQn[c * KKc + r];
    rhs[(b0 + h) * KKc + r] = acc;
  }
}

// ---------------------------------------------------------------------------
// k_cg: batched CG, axpy-form (coalesced) GEMVs, barrier-free.
// Wave b owns batch b (all LDS slices wave-private -> NO __syncthreads).
//   GEMV1: u[4q..4q+3]  += p[r] * QnT[r][4q..4q+3]   (float4, coalesced)
//   GEMV2: v[2q,2q+1]   += w[n] * Qn[n][2q,2q+1]     (float2, coalesced)
//          v[2q,2q+1]   += p[s] * C[s][2q,2q+1]      (C symmetric)
//   dots: single-wave shfl butterflies.
// Epilogue: out[4q..4q+3] = zeta(in out) + sum_r z[r]*QnT[r][4q..4q+3].
// ---------------------------------------------------------------------------
__global__ __launch_bounds__(256) void k_cg(
    const float* __restrict__ x, const float* __restrict__ Qn,
    const float* __restrict__ QnT, const float* __restrict__ C,
    const float* __restrict__ rhs, float* __restrict__ out)
{
  const int b = threadIdx.x >> 6;     // wave id = batch lane (0..3)
  const int q = threadIdx.x & 63;
  const int batch = blockIdx.x * 4 + b;

  __shared__ __align__(16) float p_lds[4][KKc];
  __shared__ __align__(16) float w_lds[4][NN_];
  __shared__ __align__(16) float z_lds[4][KKc];

  const float4* QnT4 = reinterpret_cast<const float4*>(QnT); // [r*64 + n/4]
  const float2* Qn2  = reinterpret_cast<const float2*>(Qn);  // [n*64 + r/2]
  const float2* C2   = reinterpret_cast<const float2*>(C);   // [s*64 + r/2]

  // d for this lane's 4 GEMV1 rows (n = 4q..4q+3), coalesced float4
  float4 xv = *reinterpret_cast<const float4*>(&x[batch * NN_ + 4 * q]);
  const float d0 = 1.f + xv.x * xv.x, d1 = 1.f + xv.y * xv.y,
              d2 = 1.f + xv.z * xv.z, d3 = 1.f + xv.w * xv.w;

  // CG state for rows (2q, 2q+1), coalesced float2
  float2 r2 = *reinterpret_cast<const float2*>(&rhs[batch * KKc + 2 * q]);
  float rr0 = r2.x, rr1 = r2.y;
  float z0 = 0.f, z1 = 0.f, p0 = rr0, p1 = rr1;

  float rs = rr0 * rr0 + rr1 * rr1;
#pragma unroll
  for (int m = 32; m; m >>= 1) rs += __shfl_xor(rs, m, 64);

  p_lds[b][2 * q] = p0; p_lds[b][2 * q + 1] = p1;

  const float4* pb4 = reinterpret_cast<const float4*>(p_lds[b]);
  const float4* wb4 = reinterpret_cast<const float4*>(w_lds[b]);

  for (int it = 0; it < 15; ++it) {
    // ---- GEMV1: u = Qn p (axpy over QnT rows), w = d .* u ----
    float ux = 0.f, uy = 0.f, uz = 0.f, uw = 0.f;
#pragma unroll 8
    for (int rr = 0; rr < 32; ++rr) {
      float4 p4 = pb4[rr];
      float4 m0 = QnT4[(4 * rr + 0) * 64 + q];
      float4 m1 = QnT4[(4 * rr + 1) * 64 + q];
      float4 m2 = QnT4[(4 * rr + 2) * 64 + q];
      float4 m3 = QnT4[(4 * rr + 3) * 64 + q];
      ux += p4.x * m0.x + p4.y * m1.x + p4.z * m2.x + p4.w * m3.x;
      uy += p4.x * m0.y + p4.y * m1.y + p4.z * m2.y + p4.w * m3.y;
      uz += p4.x * m0.z + p4.y * m1.z + p4.z * m2.z + p4.w * m3.z;
      uw += p4.x * m0.w + p4.y * m1.w + p4.z * m2.w + p4.w * m3.w;
    }
    float4 wv = {ux * d0, uy * d1, uz * d2, uw * d3};
    *reinterpret_cast<float4*>(&w_lds[b][4 * q]) = wv;
    // wave-private LDS: program order + lgkmcnt gives RAW correctness

    // ---- GEMV2: v = QnT w + C p (axpy over Qn rows / C rows) ----
    float vx = 0.f, vy = 0.f;
#pragma unroll 8
    for (int nn = 0; nn < 64; ++nn) {
      float4 w4 = wb4[nn];
      float2 a0 = Qn2[(4 * nn + 0) * 64 + q];
      float2 a1 = Qn2[(4 * nn + 1) * 64 + q];
      float2 a2 = Qn2[(4 * nn + 2) * 64 + q];
      float2 a3 = Qn2[(4 * nn + 3) * 64 + q];
      vx += w4.x * a0.x + w4.y * a1.x + w4.z * a2.x + w4.w * a3.x;
      vy += w4.x * a0.y + w4.y * a1.y + w4.z * a2.y + w4.w * a3.y;
    }
#pragma unroll 8
    for (int ss = 0; ss < 32; ++ss) {
      float4 p4 = pb4[ss];
      float2 c0 = C2[(4 * ss + 0) * 64 + q];
      float2 c1 = C2[(4 * ss + 1) * 64 + q];
      float2 c2 = C2[(4 * ss + 2) * 64 + q];
      float2 c3 = C2[(4 * ss + 3) * 64 + q];
      vx += p4.x * c0.x + p4.y * c1.x + p4.z * c2.x + p4.w * c3.x;
      vy += p4.x * c0.y + p4.y * c1.y + p4.z * c2.y + p4.w * c3.y;
    }

    // ---- alpha = rs / (p.v) ----
    float pv = p0 * vx + p1 * vy;
#pragma unroll
    for (int m = 32; m; m >>= 1) pv += __shfl_xor(pv, m, 64);
    float alpha = rs / (pv + 1e-30f);
    z0 += alpha * p0;  z1 += alpha * p1;
    rr0 -= alpha * vx; rr1 -= alpha * vy;

    // ---- rs_new = r.r ----
    float rsn = rr0 * rr0 + rr1 * rr1;
#pragma unroll
    for (int m = 32; m; m >>= 1) rsn += __shfl_xor(rsn, m, 64);
    float beta = rsn / (rs + 1e-30f);
    rs = rsn;
    p0 = rr0 + beta * p0; p1 = rr1 + beta * p1;

    p_lds[b][2 * q] = p0; p_lds[b][2 * q + 1] = p1;
  }

  // ---- epilogue: out = zeta(in out) + Qn z, axpy-coalesced ----
  z_lds[b][2 * q] = z0; z_lds[b][2 * q + 1] = z1;
  const float4* zb4 = reinterpret_cast<const float4*>(z_lds[b]);
  float4 o = *reinterpret_cast<const float4*>(&out[batch * NN_ + 4 * q]);
#pragma unroll 8
  for (int rr = 0; rr < 32; ++rr) {
    float4 z4 = zb4[rr];
    float4 m0 = QnT4[(4 * rr + 0) * 64 + q];
    float4 m1 = QnT4[(4 * rr + 1) * 64 + q];
    float4 m2 = QnT4[(4 * rr + 2) * 64 + q];
    float4 m3 = QnT4[(4 * rr + 3) * 64 + q];
    o.x += z4.x * m0.x + z4.y * m1.x + z4.z * m2.x + z4.w * m3.x;
    o.y += z4.x * m0.y + z4.y * m1.y + z4.z * m2.y + z4.w * m3.y;
    o.z += z4.x * m0.z + z4.y * m1.z + z4.z * m2.z + z4.w * m3.z;
    o.w += z4.x * m0.w + z4.y * m1.w + z4.z * m2.w + z4.w * m3.w;
  }
  *reinterpret_cast<float4*>(&out[batch * NN_ + 4 * q]) = o;
}

// ---------------------------------------------------------------------------
extern "C" void kernel_launch(void* const* d_in, const int* in_sizes, int n_in,
                              void* d_out, int out_size, void* d_ws, size_t ws_size,
                              hipStream_t stream)
{
  const float* x     = (const float*)d_in[0];
  const float* parms = (const float*)d_in[1];
  // d_in[2] = A : unused (cancels algebraically)
  const float* Bp    = (const float*)d_in[3];
  const float* Qf    = (const float*)d_in[4];
  const float* Wf    = (const float*)d_in[5];
  const float* Qr    = (const float*)d_in[6];
  const float* Qn    = (const float*)d_in[7];
  const float* Rr    = (const float*)d_in[8];

  // Compact workspace: 385,024 floats = 1.47 MB (proven safe in Round 4).
  float* ws   = (float*)d_ws;
  float* QfQn = ws;                 // [0      , 32768)
  float* WfQn = QfQn + 32768;       // [32768  , 40960)
  float* bb   = WfQn + 8192;        // [40960  , 172032)  bb -> zeta_r in place
  float* QrT  = bb + 131072;        // [172032 , 204800)
  float* Cm   = QrT + 32768;        // [204800 , 221184)
  float* QnT  = Cm + 16384;         // [221184 , 253952)
  float* rhs  = QnT + 32768;        // [253952 , 385024)

  float* outp = (float*)d_out;

  hipLaunchKernelGGL(k_pre2, dim3(832), dim3(256), 0, stream,
                     Qf, Qn, Wf, parms, Bp, Qr, QfQn, WfQn, bb, QrT, QnT);
  hipLaunchKernelGGL(k_pre3, dim3(80), dim3(256), 0, stream,
                     Qn, QfQn, Rr, Cm, bb);
  hipLaunchKernelGGL(k_vec, dim3(512), dim3(256), 0, stream,
                     x, parms, bb, QrT, Qn, QfQn, WfQn, outp, rhs);
  hipLaunchKernelGGL(k_cg, dim3(256), dim3(256), 0, stream,
                     x, Qn, QnT, Cm, rhs, outp);
}

// Round 6
// 484.460 us; speedup vs baseline: 2.1693x; 1.4188x over previous
//
#include <hip/hip_runtime.h>
#include <math.h>

#define BB_  1024
#define NN_  256
#define MM_  128
#define PP_  64
#define KKc  128   // N - M
#define CG_ITERS 13

// ---------------------------------------------------------------------------
// k_pre2: QfQn = Qf@Qn (256x128) | WfQn[c][r] = sum_n Wf[n][c]Qn[n][r] (64x128)
//         bb = parms@Bp.T (1024x128) | QrT[m][n] = Qr[n][m]
// ---------------------------------------------------------------------------
__global__ __launch_bounds__(256) void k_pre2(
    const float* __restrict__ Qf, const float* __restrict__ Qn,
    const float* __restrict__ Wf, const float* __restrict__ parms,
    const float* __restrict__ Bp, const float* __restrict__ Qr,
    float* __restrict__ QfQn, float* __restrict__ WfQn,
    float* __restrict__ bb, float* __restrict__ QrT)
{
  const int w = blockIdx.x, tid = threadIdx.x;
  if (w < 128) {
    __shared__ float arow[2][NN_];
    const int n0 = 2 * w;
    for (int idx = tid; idx < 2 * NN_; idx += 256)
      arow[idx >> 8][idx & 255] = Qf[(n0 + (idx >> 8)) * NN_ + (idx & 255)];
    __syncthreads();
    const int r = tid & 127, h = tid >> 7;
    float acc = 0.f;
    for (int m = 0; m < NN_; ++m) acc += arow[h][m] * Qn[m * KKc + r];
    QfQn[(n0 + h) * KKc + r] = acc;
  } else if (w < 160) {
    __shared__ float wcol[2][NN_];
    const int c0 = 2 * (w - 128);
    for (int idx = tid; idx < 2 * NN_; idx += 256)
      wcol[idx >> 8][idx & 255] = Wf[(idx & 255) * PP_ + c0 + (idx >> 8)];
    __syncthreads();
    const int r = tid & 127, h = tid >> 7;
    float acc = 0.f;
    for (int n = 0; n < NN_; ++n) acc += wcol[h][n] * Qn[n * KKc + r];
    WfQn[(c0 + h) * KKc + r] = acc;
  } else if (w < 672) {
    __shared__ float BpP[MM_ * 65];
    __shared__ float pr[2][PP_];
    const int b0 = 2 * (w - 160);
    for (int idx = tid; idx < MM_ * PP_; idx += 256) {
      int m = idx >> 6, p = idx & 63;
      BpP[m * 65 + p] = Bp[idx];
    }
    for (int idx = tid; idx < 2 * PP_; idx += 256)
      pr[idx >> 6][idx & 63] = parms[(b0 + (idx >> 6)) * PP_ + (idx & 63)];
    __syncthreads();
    const int m = tid & 127, h = tid >> 7;
    float acc = 0.f;
    for (int p = 0; p < PP_; ++p) acc += pr[h][p] * BpP[m * 65 + p];
    bb[(b0 + h) * MM_ + m] = acc;
  } else {
    const int mm = w - 672;
    QrT[mm * NN_ + tid] = Qr[tid * MM_ + mm];
  }
}

// ---------------------------------------------------------------------------
// k_pre3: C = Qn.T @ QfQn (128x128)  |  batched forward-sub: bb <- zeta_r
// ---------------------------------------------------------------------------
__global__ __launch_bounds__(256) void k_pre3(
    const float* __restrict__ Qn, const float* __restrict__ QfQn,
    const float* __restrict__ Rr, float* __restrict__ C, float* __restrict__ bb)
{
  const int w = blockIdx.x, tid = threadIdx.x;
  if (w < 64) {
    __shared__ float qcol[2][NN_];
    const int r0 = 2 * w;
    for (int idx = tid; idx < 2 * NN_; idx += 256)
      qcol[idx >> 8][idx & 255] = Qn[(idx & 255) * KKc + r0 + (idx >> 8)];
    __syncthreads();
    const int s = tid & 127, h = tid >> 7;
    float acc = 0.f;
    for (int n = 0; n < NN_; ++n) acc += qcol[h][n] * QfQn[n * KKc + s];
    C[(r0 + h) * KKc + s] = acc;
  } else {
    __shared__ float Wt[MM_ * 65];
    const int b0 = (w - 64) * 64;
    for (int idx = tid; idx < 64 * MM_; idx += 256) {
      int b = idx >> 7, m = idx & 127;
      Wt[m * 65 + b] = bb[(b0 + b) * MM_ + m];
    }
    __syncthreads();
    const int c = tid & 63, q = tid >> 6;
    if (q == 0) Wt[0 * 65 + c] /= Rr[0];
    for (int i = 0; i < MM_; ++i) {
      __syncthreads();
      float xi = Wt[i * 65 + c];
      for (int k = i + 1 + q; k < MM_; k += 4) {
        float v = Wt[k * 65 + c] - Rr[i * MM_ + k] * xi;
        if (k == i + 1) v /= Rr[k * MM_ + k];
        Wt[k * 65 + c] = v;
      }
    }
    __syncthreads();
    for (int idx = tid; idx < 64 * MM_; idx += 256) {
      int b = idx >> 7, m = idx & 127;
      bb[(b0 + b) * MM_ + m] = Wt[m * 65 + b];
    }
  }
}

// ---------------------------------------------------------------------------
// k_vec: per batch: zeta = zeta_r @ Qr.T  -> written into OUT (reused later)
//        t = (1+x^2)(x - zeta); rhs = t@Qn - zeta@QfQn - parms@WfQn
// ---------------------------------------------------------------------------
__global__ __launch_bounds__(256) void k_vec(
    const float* __restrict__ x, const float* __restrict__ parms,
    const float* __restrict__ zr, const float* __restrict__ QrT,
    const float* __restrict__ Qn, const float* __restrict__ QfQn,
    const float* __restrict__ WfQn,
    float* __restrict__ out_zeta, float* __restrict__ rhs)
{
  const int b0 = blockIdx.x * 2, tid = threadIdx.x;
  __shared__ float zrL[2][MM_], pL[2][PP_], xL[2][NN_], zL[2][NN_], tL[2][NN_];
  for (int idx = tid; idx < 2 * MM_; idx += 256)
    zrL[idx >> 7][idx & 127] = zr[(b0 + (idx >> 7)) * MM_ + (idx & 127)];
  for (int idx = tid; idx < 2 * PP_; idx += 256)
    pL[idx >> 6][idx & 63] = parms[(b0 + (idx >> 6)) * PP_ + (idx & 63)];
  for (int idx = tid; idx < 2 * NN_; idx += 256)
    xL[idx >> 8][idx & 255] = x[(b0 + (idx >> 8)) * NN_ + (idx & 255)];
  __syncthreads();
  {
    const int n = tid;
    float a0 = 0.f, a1 = 0.f;
    for (int m = 0; m < MM_; ++m) {
      float qv = QrT[m * NN_ + n];
      a0 += zrL[0][m] * qv;
      a1 += zrL[1][m] * qv;
    }
    float x0 = xL[0][n], x1 = xL[1][n];
    zL[0][n] = a0; zL[1][n] = a1;
    float t0 = (1.f + x0 * x0) * (x0 - a0);
    float t1 = (1.f + x1 * x1) * (x1 - a1);
    tL[0][n] = t0; tL[1][n] = t1;
    out_zeta[b0 * NN_ + n] = a0;
    out_zeta[(b0 + 1) * NN_ + n] = a1;
  }
  __syncthreads();
  {
    const int r = tid & 127, h = tid >> 7;
    float acc = 0.f;
    for (int n = 0; n < NN_; ++n) acc += tL[h][n] * Qn[n * KKc + r];
    for (int n = 0; n < NN_; ++n) acc -= zL[h][n] * QfQn[n * KKc + r];
    for (int c = 0; c < PP_; ++c) acc -= pL[h][c] * WfQn[c * KKc + r];
    rhs[(b0 + h) * KKc + r] = acc;
  }
}

// ---------------------------------------------------------------------------
// k_cg (v3): 4 batches per wg, 512 threads, Qn persistent in LDS [256][129]
// (odd pad -> all strided read patterns are 2-way = conflict-free).
// Role A (per thread): n = tid&255, g = tid>>8 -> batches {2g, 2g+1}:
//   u[n,b] = sum_r Qn[n][r] P[b][r]  (Qs scalar reads + uniform b128 P rows)
//   W[b][n] = d_b[n] * u[n,b]
// Role B (per thread): r = tid&127, h = tid>>7 -> batch h (2 waves/batch):
//   v[r] = sum_n Qn[n][r] W[h][n] + sum_s C[s][r] P[h][s]   (C global, coalesced)
//   CG scalars via wave shfl_xor + 16-slot LDS cross-wave combine.
// 4 barriers/iter. Epilogue: out = zeta(in out) + Qn z (role-A pattern).
// ---------------------------------------------------------------------------
__global__ __launch_bounds__(512) void k_cg(
    const float* __restrict__ x, const float* __restrict__ Qn,
    const float* __restrict__ C, const float* __restrict__ rhs,
    float* __restrict__ out)
{
  const int tid = threadIdx.x;
  const int nA = tid & 255, g = tid >> 8;        // role A
  const int rB = tid & 127, h = tid >> 7;        // role B (batch = h)
  const int wid = tid >> 6;                      // wave 0..7
  const int lane = tid & 63;
  const int bg0 = blockIdx.x * 4;

  __shared__ float Qs[NN_ * 129];                // Qn[n][r] at n*129+r
  __shared__ __align__(16) float Pl[4][KKc];     // P[b][r]
  __shared__ __align__(16) float Wl[4][NN_];     // W[b][n]
  __shared__ float red[16];

  // ---- stage Qn -> LDS (coalesced global float4, scalar LDS writes) ----
  for (int j = 0; j < 16; ++j) {
    int f4 = j * 512 + tid;                      // 8192 float4s
    float4 v = reinterpret_cast<const float4*>(Qn)[f4];
    int f = f4 * 4, n = f >> 7, r = f & 127;
    Qs[n * 129 + r + 0] = v.x;
    Qs[n * 129 + r + 1] = v.y;
    Qs[n * 129 + r + 2] = v.z;
    Qs[n * 129 + r + 3] = v.w;
  }

  // ---- role-A constants: d for batches 2g, 2g+1 at row nA ----
  float xa0 = x[(bg0 + 2 * g) * NN_ + nA];
  float xa1 = x[(bg0 + 2 * g + 1) * NN_ + nA];
  const float dA0 = 1.f + xa0 * xa0;
  const float dA1 = 1.f + xa1 * xa1;

  // ---- role-B init: p = r = rhs ----
  float rr = rhs[(bg0 + h) * KKc + rB];
  float p = rr, z = 0.f;
  Pl[h][rB] = p;

  float t = rr * rr;
#pragma unroll
  for (int m = 32; m; m >>= 1) t += __shfl_xor(t, m, 64);
  if (lane == 0) red[wid] = t;
  __syncthreads();
  float rs = red[2 * h] + red[2 * h + 1];
  __syncthreads();

  for (int it = 0; it < CG_ITERS; ++it) {
    // ---- role A: u = Qn p for 2 batches; W = d .* u ----
    float u0 = 0.f, u1 = 0.f;
#pragma unroll 8
    for (int r4 = 0; r4 < KKc; r4 += 4) {
      float q0 = Qs[nA * 129 + r4 + 0];
      float q1 = Qs[nA * 129 + r4 + 1];
      float q2 = Qs[nA * 129 + r4 + 2];
      float q3 = Qs[nA * 129 + r4 + 3];
      float4 pa = *reinterpret_cast<const float4*>(&Pl[2 * g][r4]);
      float4 pb = *reinterpret_cast<const float4*>(&Pl[2 * g + 1][r4]);
      u0 += q0 * pa.x + q1 * pa.y + q2 * pa.z + q3 * pa.w;
      u1 += q0 * pb.x + q1 * pb.y + q2 * pb.z + q3 * pb.w;
    }
    Wl[2 * g][nA] = dA0 * u0;
    Wl[2 * g + 1][nA] = dA1 * u1;
    __syncthreads();

    // ---- role B: v = QnT W + C p  (batch h) ----
    float v = 0.f;
#pragma unroll 8
    for (int n4 = 0; n4 < NN_; n4 += 4) {
      float q0 = Qs[(n4 + 0) * 129 + rB];
      float q1 = Qs[(n4 + 1) * 129 + rB];
      float q2 = Qs[(n4 + 2) * 129 + rB];
      float q3 = Qs[(n4 + 3) * 129 + rB];
      float4 wv = *reinterpret_cast<const float4*>(&Wl[h][n4]);
      v += q0 * wv.x + q1 * wv.y + q2 * wv.z + q3 * wv.w;
    }
#pragma unroll 8
    for (int s4 = 0; s4 < KKc; s4 += 4) {
      float c0 = C[(s4 + 0) * KKc + rB];
      float c1 = C[(s4 + 1) * KKc + rB];
      float c2 = C[(s4 + 2) * KKc + rB];
      float c3 = C[(s4 + 3) * KKc + rB];
      float4 pv4 = *reinterpret_cast<const float4*>(&Pl[h][s4]);
      v += c0 * pv4.x + c1 * pv4.y + c2 * pv4.z + c3 * pv4.w;
    }

    // ---- pv reduction (2 waves per batch) ----
    float pv = p * v;
#pragma unroll
    for (int m = 32; m; m >>= 1) pv += __shfl_xor(pv, m, 64);
    if (lane == 0) red[wid] = pv;
    __syncthreads();
    float pvb = red[2 * h] + red[2 * h + 1];
    float alpha = rs / (pvb + 1e-30f);
    z += alpha * p;
    rr -= alpha * v;

    float rn = rr * rr;
#pragma unroll
    for (int m = 32; m; m >>= 1) rn += __shfl_xor(rn, m, 64);
    if (lane == 0) red[8 + wid] = rn;
    __syncthreads();
    float rsn = red[8 + 2 * h] + red[8 + 2 * h + 1];
    float beta = rsn / (rs + 1e-30f);
    rs = rsn;
    p = rr + beta * p;
    Pl[h][rB] = p;
    __syncthreads();
  }

  // ---- epilogue: Pl <- z ; out = zeta(in out) + Qn z ----
  Pl[h][rB] = z;
  __syncthreads();
  float o0 = 0.f, o1 = 0.f;
#pragma unroll 8
  for (int r4 = 0; r4 < KKc; r4 += 4) {
    float q0 = Qs[nA * 129 + r4 + 0];
    float q1 = Qs[nA * 129 + r4 + 1];
    float q2 = Qs[nA * 129 + r4 + 2];
    float q3 = Qs[nA * 129 + r4 + 3];
    float4 za = *reinterpret_cast<const float4*>(&Pl[2 * g][r4]);
    float4 zb = *reinterpret_cast<const float4*>(&Pl[2 * g + 1][r4]);
    o0 += q0 * za.x + q1 * za.y + q2 * za.z + q3 * za.w;
    o1 += q0 * zb.x + q1 * zb.y + q2 * zb.z + q3 * zb.w;
  }
  out[(bg0 + 2 * g) * NN_ + nA] += o0;
  out[(bg0 + 2 * g + 1) * NN_ + nA] += o1;
}

// ---------------------------------------------------------------------------
extern "C" void kernel_launch(void* const* d_in, const int* in_sizes, int n_in,
                              void* d_out, int out_size, void* d_ws, size_t ws_size,
                              hipStream_t stream)
{
  const float* x     = (const float*)d_in[0];
  const float* parms = (const float*)d_in[1];
  // d_in[2] = A : unused (cancels algebraically)
  const float* Bp    = (const float*)d_in[3];
  const float* Qf    = (const float*)d_in[4];
  const float* Wf    = (const float*)d_in[5];
  const float* Qr    = (const float*)d_in[6];
  const float* Qn    = (const float*)d_in[7];
  const float* Rr    = (const float*)d_in[8];

  // Workspace: 352,256 floats = 1.34 MB (proven-safe region).
  float* ws   = (float*)d_ws;
  float* QfQn = ws;                 // [0      , 32768)
  float* WfQn = QfQn + 32768;       // [32768  , 40960)
  float* bb   = WfQn + 8192;        // [40960  , 172032)  bb -> zeta_r in place
  float* QrT  = bb + 131072;        // [172032 , 204800)
  float* Cm   = QrT + 32768;        // [204800 , 221184)
  float* rhs  = Cm + 16384;         // [221184 , 352256)

  float* outp = (float*)d_out;

  hipLaunchKernelGGL(k_pre2, dim3(800), dim3(256), 0, stream,
                     Qf, Qn, Wf, parms, Bp, Qr, QfQn, WfQn, bb, QrT);
  hipLaunchKernelGGL(k_pre3, dim3(80), dim3(256), 0, stream,
                     Qn, QfQn, Rr, Cm, bb);
  hipLaunchKernelGGL(k_vec, dim3(512), dim3(256), 0, stream,
                     x, parms, bb, QrT, Qn, QfQn, WfQn, outp, rhs);
  hipLaunchKernelGGL(k_cg, dim3(256), dim3(512), 0, stream,
                     x, Qn, Cm, rhs, outp);
}

// Round 7
// 233.942 us; speedup vs baseline: 4.4923x; 2.0709x over previous
//
#include <hip/hip_runtime.h>
#include <math.h>

#define BB_  1024
#define NN_  256
#define MM_  128
#define PP_  64
#define KKc  128   // N - M
#define CG_ITERS 13

// ---------------------------------------------------------------------------
// kA: QfQn = Qf@Qn (256x128) | WfQn[c][r] (64x128) |
//     GT[j][m] = (Rr^-1 Qr^T)[m][j]  via wave-per-column back-substitution
// ---------------------------------------------------------------------------
__global__ __launch_bounds__(256) void kA(
    const float* __restrict__ Qf, const float* __restrict__ Qn,
    const float* __restrict__ Wf, const float* __restrict__ Qr,
    const float* __restrict__ Rr,
    float* __restrict__ QfQn, float* __restrict__ WfQn,
    float* __restrict__ GT)
{
  __shared__ float smem[MM_ * 129];   // union across branches
  const int w = blockIdx.x, tid = threadIdx.x;
  if (w < 128) {
    float* arow = smem;               // [2][256]
    const int n0 = 2 * w;
    for (int idx = tid; idx < 2 * NN_; idx += 256)
      arow[idx] = Qf[(n0 + (idx >> 8)) * NN_ + (idx & 255)];
    __syncthreads();
    const int r = tid & 127, h = tid >> 7;
    float acc = 0.f;
    for (int m = 0; m < NN_; ++m) acc += arow[h * NN_ + m] * Qn[m * KKc + r];
    QfQn[(n0 + h) * KKc + r] = acc;
  } else if (w < 160) {
    float* wcol = smem;               // [2][256]
    const int c0 = 2 * (w - 128);
    for (int idx = tid; idx < 2 * NN_; idx += 256)
      wcol[idx] = Wf[(idx & 255) * PP_ + c0 + (idx >> 8)];
    __syncthreads();
    const int r = tid & 127, h = tid >> 7;
    float acc = 0.f;
    for (int n = 0; n < NN_; ++n) acc += wcol[h * NN_ + n] * Qn[n * KKc + r];
    WfQn[(c0 + h) * KKc + r] = acc;
  } else {
    // ---- G-solve: Rr (upper-tri) G[:,j] = Qr^T[:,j];  GT[j][:] = G[:,j] ----
    float* Rs = smem;                 // [128][129]
    for (int idx = tid; idx < MM_ * MM_; idx += 256)
      Rs[(idx >> 7) * 129 + (idx & 127)] = Rr[idx];
    __syncthreads();
    const int wv = tid >> 6, l = tid & 63;
    const int j = (w - 160) * 4 + wv;            // column 0..255
    float q0 = Qr[j * MM_ + l];                  // Qr^T[:,j] = Qr[j,:]
    float q1 = Qr[j * MM_ + 64 + l];
    float g0 = 0.f, g1 = 0.f;
    for (int k = MM_ - 1; k >= 0; --k) {
      float src = (k >= 64) ? q1 : q0;
      float num = __shfl(src, k & 63, 64);
      float gk = num / Rs[k * 129 + k];
      if (k >= 64) { if (l == k - 64) g1 = gk; }
      else         { if (l == k)     g0 = gk; }
      if (l < k)      q0 -= Rs[l * 129 + k] * gk;
      if (l + 64 < k) q1 -= Rs[(l + 64) * 129 + k] * gk;
    }
    GT[j * MM_ + l]      = g0;
    GT[j * MM_ + 64 + l] = g1;
  }
}

// ---------------------------------------------------------------------------
// kB: C = Qn.T @ QfQn (128x128) | H[p][j] = sum_m Bp[m][p] GT[j][m] (64x256)
// ---------------------------------------------------------------------------
__global__ __launch_bounds__(256) void kB(
    const float* __restrict__ Qn, const float* __restrict__ QfQn,
    const float* __restrict__ Bp, const float* __restrict__ GT,
    float* __restrict__ C, float* __restrict__ H)
{
  __shared__ float smem[MM_ * 65 + 16 * MM_];   // Bp[128][65] + GT rows [16][128]
  const int w = blockIdx.x, tid = threadIdx.x;
  if (w < 64) {
    float* qcol = smem;               // [2][256]
    const int r0 = 2 * w;
    for (int idx = tid; idx < 2 * NN_; idx += 256)
      qcol[idx] = Qn[(idx & 255) * KKc + r0 + (idx >> 8)];
    __syncthreads();
    const int s = tid & 127, h = tid >> 7;
    float acc = 0.f;
    for (int n = 0; n < NN_; ++n) acc += qcol[h * NN_ + n] * QfQn[n * KKc + s];
    C[(r0 + h) * KKc + s] = acc;
  } else {
    float* Bl = smem;                 // [128][65]
    float* Gl = smem + MM_ * 65;      // [16][128]
    const int j0 = (w - 64) * 16;
    for (int idx = tid; idx < MM_ * PP_; idx += 256)
      Bl[(idx >> 6) * 65 + (idx & 63)] = Bp[idx];
    for (int idx = tid; idx < 16 * MM_; idx += 256)
      Gl[idx] = GT[j0 * MM_ + idx];
    __syncthreads();
    const int p = tid & 63, jj = tid >> 6;
    for (int jl = jj; jl < 16; jl += 4) {
      float acc = 0.f;
      for (int m = 0; m < MM_; ++m) acc += Bl[m * 65 + p] * Gl[jl * MM_ + m];
      H[p * NN_ + j0 + jl] = acc;
    }
  }
}

// ---------------------------------------------------------------------------
// kC: W2[p][r] = sum_n H[p][n] QfQn[n][r] + WfQn[p][r]   (64x128)
// ---------------------------------------------------------------------------
__global__ __launch_bounds__(256) void kC(
    const float* __restrict__ H, const float* __restrict__ QfQn,
    const float* __restrict__ WfQn, float* __restrict__ W2)
{
  const int tid = threadIdx.x;
  const int p = blockIdx.x * 2 + (tid >> 7), r = tid & 127;
  float acc = WfQn[p * KKc + r];
  for (int n = 0; n < NN_; ++n) acc += H[p * NN_ + n] * QfQn[n * KKc + r];
  W2[p * KKc + r] = acc;
}

// ---------------------------------------------------------------------------
// k_vec: per batch (2/wg): zeta = parms@H -> OUT ; t = (1+x^2)(x - zeta)
//        rhs = t@Qn - parms@W2
// ---------------------------------------------------------------------------
__global__ __launch_bounds__(256) void k_vec(
    const float* __restrict__ x, const float* __restrict__ parms,
    const float* __restrict__ H, const float* __restrict__ Qn,
    const float* __restrict__ W2,
    float* __restrict__ out_zeta, float* __restrict__ rhs)
{
  const int b0 = blockIdx.x * 2, tid = threadIdx.x;
  __shared__ float pL[2][PP_], xL[2][NN_], tL[2][NN_];
  for (int idx = tid; idx < 2 * PP_; idx += 256)
    pL[idx >> 6][idx & 63] = parms[(b0 + (idx >> 6)) * PP_ + (idx & 63)];
  for (int idx = tid; idx < 2 * NN_; idx += 256)
    xL[idx >> 8][idx & 255] = x[(b0 + (idx >> 8)) * NN_ + (idx & 255)];
  __syncthreads();
  {
    const int n = tid;
    float a0 = 0.f, a1 = 0.f;
    for (int p = 0; p < PP_; ++p) {
      float hv = H[p * NN_ + n];
      a0 += pL[0][p] * hv;
      a1 += pL[1][p] * hv;
    }
    float x0 = xL[0][n], x1 = xL[1][n];
    tL[0][n] = (1.f + x0 * x0) * (x0 - a0);
    tL[1][n] = (1.f + x1 * x1) * (x1 - a1);
    out_zeta[b0 * NN_ + n] = a0;
    out_zeta[(b0 + 1) * NN_ + n] = a1;
  }
  __syncthreads();
  {
    const int r = tid & 127, h = tid >> 7;
    float acc = 0.f;
    for (int n = 0; n < NN_; ++n) acc += tL[h][n] * Qn[n * KKc + r];
    for (int p = 0; p < PP_; ++p) acc -= pL[h][p] * W2[p * KKc + r];
    rhs[(b0 + h) * KKc + r] = acc;
  }
}

// ---------------------------------------------------------------------------
// k_cg: 4 batches per wg, 512 threads, Qn persistent in LDS [256][129].
// (carried verbatim from Round 6 — passed, no longer dominant)
// ---------------------------------------------------------------------------
__global__ __launch_bounds__(512) void k_cg(
    const float* __restrict__ x, const float* __restrict__ Qn,
    const float* __restrict__ C, const float* __restrict__ rhs,
    float* __restrict__ out)
{
  const int tid = threadIdx.x;
  const int nA = tid & 255, g = tid >> 8;        // role A
  const int rB = tid & 127, h = tid >> 7;        // role B (batch = h)
  const int wid = tid >> 6;                      // wave 0..7
  const int lane = tid & 63;
  const int bg0 = blockIdx.x * 4;

  __shared__ float Qs[NN_ * 129];
  __shared__ __align__(16) float Pl[4][KKc];
  __shared__ __align__(16) float Wl[4][NN_];
  __shared__ float red[16];

  for (int j = 0; j < 16; ++j) {
    int f4 = j * 512 + tid;
    float4 v = reinterpret_cast<const float4*>(Qn)[f4];
    int f = f4 * 4, n = f >> 7, r = f & 127;
    Qs[n * 129 + r + 0] = v.x;
    Qs[n * 129 + r + 1] = v.y;
    Qs[n * 129 + r + 2] = v.z;
    Qs[n * 129 + r + 3] = v.w;
  }

  float xa0 = x[(bg0 + 2 * g) * NN_ + nA];
  float xa1 = x[(bg0 + 2 * g + 1) * NN_ + nA];
  const float dA0 = 1.f + xa0 * xa0;
  const float dA1 = 1.f + xa1 * xa1;

  float rr = rhs[(bg0 + h) * KKc + rB];
  float p = rr, z = 0.f;
  Pl[h][rB] = p;

  float t = rr * rr;
#pragma unroll
  for (int m = 32; m; m >>= 1) t += __shfl_xor(t, m, 64);
  if (lane == 0) red[wid] = t;
  __syncthreads();
  float rs = red[2 * h] + red[2 * h + 1];
  __syncthreads();

  for (int it = 0; it < CG_ITERS; ++it) {
    float u0 = 0.f, u1 = 0.f;
#pragma unroll 8
    for (int r4 = 0; r4 < KKc; r4 += 4) {
      float q0 = Qs[nA * 129 + r4 + 0];
      float q1 = Qs[nA * 129 + r4 + 1];
      float q2 = Qs[nA * 129 + r4 + 2];
      float q3 = Qs[nA * 129 + r4 + 3];
      float4 pa = *reinterpret_cast<const float4*>(&Pl[2 * g][r4]);
      float4 pb = *reinterpret_cast<const float4*>(&Pl[2 * g + 1][r4]);
      u0 += q0 * pa.x + q1 * pa.y + q2 * pa.z + q3 * pa.w;
      u1 += q0 * pb.x + q1 * pb.y + q2 * pb.z + q3 * pb.w;
    }
    Wl[2 * g][nA] = dA0 * u0;
    Wl[2 * g + 1][nA] = dA1 * u1;
    __syncthreads();

    float v = 0.f;
#pragma unroll 8
    for (int n4 = 0; n4 < NN_; n4 += 4) {
      float q0 = Qs[(n4 + 0) * 129 + rB];
      float q1 = Qs[(n4 + 1) * 129 + rB];
      float q2 = Qs[(n4 + 2) * 129 + rB];
      float q3 = Qs[(n4 + 3) * 129 + rB];
      float4 wv = *reinterpret_cast<const float4*>(&Wl[h][n4]);
      v += q0 * wv.x + q1 * wv.y + q2 * wv.z + q3 * wv.w;
    }
#pragma unroll 8
    for (int s4 = 0; s4 < KKc; s4 += 4) {
      float c0 = C[(s4 + 0) * KKc + rB];
      float c1 = C[(s4 + 1) * KKc + rB];
      float c2 = C[(s4 + 2) * KKc + rB];
      float c3 = C[(s4 + 3) * KKc + rB];
      float4 pv4 = *reinterpret_cast<const float4*>(&Pl[h][s4]);
      v += c0 * pv4.x + c1 * pv4.y + c2 * pv4.z + c3 * pv4.w;
    }

    float pv = p * v;
#pragma unroll
    for (int m = 32; m; m >>= 1) pv += __shfl_xor(pv, m, 64);
    if (lane == 0) red[wid] = pv;
    __syncthreads();
    float pvb = red[2 * h] + red[2 * h + 1];
    float alpha = rs / (pvb + 1e-30f);
    z += alpha * p;
    rr -= alpha * v;

    float rn = rr * rr;
#pragma unroll
    for (int m = 32; m; m >>= 1) rn += __shfl_xor(rn, m, 64);
    if (lane == 0) red[8 + wid] = rn;
    __syncthreads();
    float rsn = red[8 + 2 * h] + red[8 + 2 * h + 1];
    float beta = rsn / (rs + 1e-30f);
    rs = rsn;
    p = rr + beta * p;
    Pl[h][rB] = p;
    __syncthreads();
  }

  Pl[h][rB] = z;
  __syncthreads();
  float o0 = 0.f, o1 = 0.f;
#pragma unroll 8
  for (int r4 = 0; r4 < KKc; r4 += 4) {
    float q0 = Qs[nA * 129 + r4 + 0];
    float q1 = Qs[nA * 129 + r4 + 1];
    float q2 = Qs[nA * 129 + r4 + 2];
    float q3 = Qs[nA * 129 + r4 + 3];
    float4 za = *reinterpret_cast<const float4*>(&Pl[2 * g][r4]);
    float4 zb = *reinterpret_cast<const float4*>(&Pl[2 * g + 1][r4]);
    o0 += q0 * za.x + q1 * za.y + q2 * za.z + q3 * za.w;
    o1 += q0 * zb.x + q1 * zb.y + q2 * zb.z + q3 * zb.w;
  }
  out[(bg0 + 2 * g) * NN_ + nA] += o0;
  out[(bg0 + 2 * g + 1) * NN_ + nA] += o1;
}

// ---------------------------------------------------------------------------
extern "C" void kernel_launch(void* const* d_in, const int* in_sizes, int n_in,
                              void* d_out, int out_size, void* d_ws, size_t ws_size,
                              hipStream_t stream)
{
  const float* x     = (const float*)d_in[0];
  const float* parms = (const float*)d_in[1];
  // d_in[2] = A : unused (cancels algebraically)
  const float* Bp    = (const float*)d_in[3];
  const float* Qf    = (const float*)d_in[4];
  const float* Wf    = (const float*)d_in[5];
  const float* Qr    = (const float*)d_in[6];
  const float* Qn    = (const float*)d_in[7];
  const float* Rr    = (const float*)d_in[8];

  // Workspace: 245,760 floats = 0.94 MB (well inside proven-safe region).
  float* ws   = (float*)d_ws;
  float* QfQn = ws;                 // [0      , 32768)
  float* WfQn = QfQn + 32768;       // [32768  , 40960)
  float* GT   = WfQn + 8192;        // [40960  , 73728)   GT[j][m] (256x128)
  float* H    = GT + 32768;         // [73728  , 90112)   H[p][n]  (64x256)
  float* Cm   = H + 16384;          // [90112  , 106496)  C (128x128)
  float* W2   = Cm + 16384;         // [106496 , 114688)  W2[p][r] (64x128)
  float* rhs  = W2 + 8192;          // [114688 , 245760)

  float* outp = (float*)d_out;

  hipLaunchKernelGGL(kA, dim3(224), dim3(256), 0, stream,
                     Qf, Qn, Wf, Qr, Rr, QfQn, WfQn, GT);
  hipLaunchKernelGGL(kB, dim3(80), dim3(256), 0, stream,
                     Qn, QfQn, Bp, GT, Cm, H);
  hipLaunchKernelGGL(kC, dim3(32), dim3(256), 0, stream,
                     H, QfQn, WfQn, W2);
  hipLaunchKernelGGL(k_vec, dim3(512), dim3(256), 0, stream,
                     x, parms, H, Qn, W2, outp, rhs);
  hipLaunchKernelGGL(k_cg, dim3(256), dim3(512), 0, stream,
                     x, Qn, Cm, rhs, outp);
}

// Round 9
// 215.367 us; speedup vs baseline: 4.8798x; 1.0862x over previous
//
#include <hip/hip_runtime.h>
#include <math.h>

#define BB_  1024
#define NN_  256
#define MM_  128
#define PP_  64
#define KKc  128   // N - M
#define CG_ITERS 13
#define QSTRIDE 132   // 128 cols + pad 4 (row base 528B = 33*16B -> b128-aligned)

// ---------------------------------------------------------------------------
// kA: QfQn = Qf@Qn (256x128) | WfQn[c][r] (64x128) |
//     GT[j][m] = (Rr^-1 Qr^T)[m][j]  via wave-per-column back-substitution
// ---------------------------------------------------------------------------
__global__ __launch_bounds__(256) void kA(
    const float* __restrict__ Qf, const float* __restrict__ Qn,
    const float* __restrict__ Wf, const float* __restrict__ Qr,
    const float* __restrict__ Rr,
    float* __restrict__ QfQn, float* __restrict__ WfQn,
    float* __restrict__ GT)
{
  __shared__ float smem[MM_ * 129];   // union across branches
  const int w = blockIdx.x, tid = threadIdx.x;
  if (w < 128) {
    float* arow = smem;               // [2][256]
    const int n0 = 2 * w;
    for (int idx = tid; idx < 2 * NN_; idx += 256)
      arow[idx] = Qf[(n0 + (idx >> 8)) * NN_ + (idx & 255)];
    __syncthreads();
    const int r = tid & 127, h = tid >> 7;
    float acc = 0.f;
    for (int m = 0; m < NN_; ++m) acc += arow[h * NN_ + m] * Qn[m * KKc + r];
    QfQn[(n0 + h) * KKc + r] = acc;
  } else if (w < 160) {
    float* wcol = smem;               // [2][256]
    const int c0 = 2 * (w - 128);
    for (int idx = tid; idx < 2 * NN_; idx += 256)
      wcol[idx] = Wf[(idx & 255) * PP_ + c0 + (idx >> 8)];
    __syncthreads();
    const int r = tid & 127, h = tid >> 7;
    float acc = 0.f;
    for (int n = 0; n < NN_; ++n) acc += wcol[h * NN_ + n] * Qn[n * KKc + r];
    WfQn[(c0 + h) * KKc + r] = acc;
  } else {
    // ---- G-solve: Rr (upper-tri) G[:,j] = Qr^T[:,j];  GT[j][:] = G[:,j] ----
    float* Rs = smem;                 // [128][129]
    for (int idx = tid; idx < MM_ * MM_; idx += 256)
      Rs[(idx >> 7) * 129 + (idx & 127)] = Rr[idx];
    __syncthreads();
    const int wv = tid >> 6, l = tid & 63;
    const int j = (w - 160) * 4 + wv;            // column 0..255
    float q0 = Qr[j * MM_ + l];                  // Qr^T[:,j] = Qr[j,:]
    float q1 = Qr[j * MM_ + 64 + l];
    float g0 = 0.f, g1 = 0.f;
    for (int k = MM_ - 1; k >= 0; --k) {
      float src = (k >= 64) ? q1 : q0;
      float num = __shfl(src, k & 63, 64);
      float gk = num / Rs[k * 129 + k];
      if (k >= 64) { if (l == k - 64) g1 = gk; }
      else         { if (l == k)     g0 = gk; }
      if (l < k)      q0 -= Rs[l * 129 + k] * gk;
      if (l + 64 < k) q1 -= Rs[(l + 64) * 129 + k] * gk;
    }
    GT[j * MM_ + l]      = g0;
    GT[j * MM_ + 64 + l] = g1;
  }
}

// ---------------------------------------------------------------------------
// kB: C = Qn.T @ QfQn (128x128) | H[p][j] = sum_m Bp[m][p] GT[j][m] (64x256)
// ---------------------------------------------------------------------------
__global__ __launch_bounds__(256) void kB(
    const float* __restrict__ Qn, const float* __restrict__ QfQn,
    const float* __restrict__ Bp, const float* __restrict__ GT,
    float* __restrict__ C, float* __restrict__ H)
{
  __shared__ float smem[MM_ * 65 + 16 * MM_];   // Bp[128][65] + GT rows [16][128]
  const int w = blockIdx.x, tid = threadIdx.x;
  if (w < 64) {
    float* qcol = smem;               // [2][256]
    const int r0 = 2 * w;
    for (int idx = tid; idx < 2 * NN_; idx += 256)
      qcol[idx] = Qn[(idx & 255) * KKc + r0 + (idx >> 8)];
    __syncthreads();
    const int s = tid & 127, h = tid >> 7;
    float acc = 0.f;
    for (int n = 0; n < NN_; ++n) acc += qcol[h * NN_ + n] * QfQn[n * KKc + s];
    C[(r0 + h) * KKc + s] = acc;
  } else {
    float* Bl = smem;                 // [128][65]
    float* Gl = smem + MM_ * 65;      // [16][128]
    const int j0 = (w - 64) * 16;
    for (int idx = tid; idx < MM_ * PP_; idx += 256)
      Bl[(idx >> 6) * 65 + (idx & 63)] = Bp[idx];
    for (int idx = tid; idx < 16 * MM_; idx += 256)
      Gl[idx] = GT[j0 * MM_ + idx];
    __syncthreads();
    const int p = tid & 63, jj = tid >> 6;
    for (int jl = jj; jl < 16; jl += 4) {
      float acc = 0.f;
      for (int m = 0; m < MM_; ++m) acc += Bl[m * 65 + p] * Gl[jl * MM_ + m];
      H[p * NN_ + j0 + jl] = acc;
    }
  }
}

// ---------------------------------------------------------------------------
// kC: W2[p][r] = sum_n H[p][n] QfQn[n][r] + WfQn[p][r]   (64x128)
// ---------------------------------------------------------------------------
__global__ __launch_bounds__(256) void kC(
    const float* __restrict__ H, const float* __restrict__ QfQn,
    const float* __restrict__ WfQn, float* __restrict__ W2)
{
  const int tid = threadIdx.x;
  const int p = blockIdx.x * 2 + (tid >> 7), r = tid & 127;
  float acc = WfQn[p * KKc + r];
  for (int n = 0; n < NN_; ++n) acc += H[p * NN_ + n] * QfQn[n * KKc + r];
  W2[p * KKc + r] = acc;
}

// ---------------------------------------------------------------------------
// k_vec: per batch (2/wg): zeta = parms@H -> OUT ; t = (1+x^2)(x - zeta)
//        rhs = t@Qn - parms@W2
// ---------------------------------------------------------------------------
__global__ __launch_bounds__(256) void k_vec(
    const float* __restrict__ x, const float* __restrict__ parms,
    const float* __restrict__ H, const float* __restrict__ Qn,
    const float* __restrict__ W2,
    float* __restrict__ out_zeta, float* __restrict__ rhs)
{
  const int b0 = blockIdx.x * 2, tid = threadIdx.x;
  __shared__ float pL[2][PP_], xL[2][NN_], tL[2][NN_];
  for (int idx = tid; idx < 2 * PP_; idx += 256)
    pL[idx >> 6][idx & 63] = parms[(b0 + (idx >> 6)) * PP_ + (idx & 63)];
  for (int idx = tid; idx < 2 * NN_; idx += 256)
    xL[idx >> 8][idx & 255] = x[(b0 + (idx >> 8)) * NN_ + (idx & 255)];
  __syncthreads();
  {
    const int n = tid;
    float a0 = 0.f, a1 = 0.f;
    for (int p = 0; p < PP_; ++p) {
      float hv = H[p * NN_ + n];
      a0 += pL[0][p] * hv;
      a1 += pL[1][p] * hv;
    }
    float x0 = xL[0][n], x1 = xL[1][n];
    tL[0][n] = (1.f + x0 * x0) * (x0 - a0);
    tL[1][n] = (1.f + x1 * x1) * (x1 - a1);
    out_zeta[b0 * NN_ + n] = a0;
    out_zeta[(b0 + 1) * NN_ + n] = a1;
  }
  __syncthreads();
  {
    const int r = tid & 127, h = tid >> 7;
    float acc = 0.f;
    for (int n = 0; n < NN_; ++n) acc += tL[h][n] * Qn[n * KKc + r];
    for (int p = 0; p < PP_; ++p) acc -= pL[h][p] * W2[p * KKc + r];
    rhs[(b0 + h) * KKc + r] = acc;
  }
}

// ---------------------------------------------------------------------------
// k_cg (v5 = R8 minus fused-recurrence): 4 batches/wg, 512 threads.
//  (a) Qn in LDS [256][132], b128 staging + b128 role-A row reads  [KEPT]
//  (b) C row rB hoisted to 32xfloat4 registers ((C.p)[rB] via row dot) [KEPT]
//  (c) reductions: R7's two-phase DIRECT r.r reduction, red[16], 4 bar/iter
//      [REVERTED - bisection target]
// ---------------------------------------------------------------------------
__global__ __launch_bounds__(512, 2) void k_cg(
    const float* __restrict__ x, const float* __restrict__ Qn,
    const float* __restrict__ C, const float* __restrict__ rhs,
    float* __restrict__ out)
{
  const int tid = threadIdx.x;
  const int nA = tid & 255, g2 = tid >> 8;       // role A: batches 2g2, 2g2+1
  const int rB = tid & 127, h = tid >> 7;        // role B: batch h
  const int wid = tid >> 6, lane = tid & 63;
  const int bg0 = blockIdx.x * 4;

  __shared__ __align__(16) float Qs[NN_ * QSTRIDE];
  __shared__ __align__(16) float Pl[4][KKc];
  __shared__ __align__(16) float Wl[4][NN_];
  __shared__ float red[16];

  // ---- stage Qn -> LDS [256][132] with b128 writes ----
  for (int j = 0; j < 16; ++j) {
    int f4 = j * 512 + tid;
    int n = f4 >> 5, g = f4 & 31;
    float4 v = reinterpret_cast<const float4*>(Qn)[f4];
    *reinterpret_cast<float4*>(&Qs[n * QSTRIDE + 4 * g]) = v;
  }

  // ---- hoist C row rB into registers: (C.p)[rB] = row(rB) . p ----
  float4 creg[32];
#pragma unroll
  for (int j = 0; j < 32; ++j)
    creg[j] = reinterpret_cast<const float4*>(C)[rB * 32 + j];

  // ---- role-A constants ----
  float xa0 = x[(bg0 + 2 * g2) * NN_ + nA];
  float xa1 = x[(bg0 + 2 * g2 + 1) * NN_ + nA];
  const float dA0 = 1.f + xa0 * xa0;
  const float dA1 = 1.f + xa1 * xa1;

  // ---- role-B init: p = r = rhs ----
  float rr = rhs[(bg0 + h) * KKc + rB];
  float p = rr, z = 0.f;
  Pl[h][rB] = p;

  float t = rr * rr;
#pragma unroll
  for (int m = 32; m; m >>= 1) t += __shfl_xor(t, m, 64);
  if (lane == 0) red[wid] = t;
  __syncthreads();
  float rs = red[2 * h] + red[2 * h + 1];

  const float4* PlA0 = reinterpret_cast<const float4*>(Pl[2 * g2]);
  const float4* PlA1 = reinterpret_cast<const float4*>(Pl[2 * g2 + 1]);
  const float4* PlB  = reinterpret_cast<const float4*>(Pl[h]);

  for (int it = 0; it < CG_ITERS; ++it) {
    // ---- role A: u = Qn p (b128 row reads + float4 P broadcast) ----
    float u0 = 0.f, u1 = 0.f;
#pragma unroll 8
    for (int gp = 0; gp < 32; ++gp) {
      float4 q = *reinterpret_cast<const float4*>(&Qs[nA * QSTRIDE + 4 * gp]);
      float4 pa = PlA0[gp];
      float4 pb = PlA1[gp];
      u0 += q.x * pa.x + q.y * pa.y + q.z * pa.z + q.w * pa.w;
      u1 += q.x * pb.x + q.y * pb.y + q.z * pb.z + q.w * pb.w;
    }
    Wl[2 * g2][nA] = dA0 * u0;
    Wl[2 * g2 + 1][nA] = dA1 * u1;
    __syncthreads();                             // bar 1: W ready

    // ---- role B: v = QnT W (column reads) + C p (registers) ----
    float v = 0.f;
#pragma unroll 8
    for (int n = 0; n < NN_; ++n)
      v += Qs[n * QSTRIDE + rB] * Wl[h][n];
#pragma unroll
    for (int j = 0; j < 32; ++j) {
      float4 p4 = PlB[j];
      float4 c4 = creg[j];
      v += c4.x * p4.x + c4.y * p4.y + c4.z * p4.z + c4.w * p4.w;
    }

    // ---- pv reduction (R7 structure) ----
    float pv = p * v;
#pragma unroll
    for (int m = 32; m; m >>= 1) pv += __shfl_xor(pv, m, 64);
    if (lane == 0) red[wid] = pv;
    __syncthreads();                             // bar 2
    float pvb = red[2 * h] + red[2 * h + 1];
    float alpha = rs / (pvb + 1e-30f);
    z += alpha * p;
    rr -= alpha * v;

    // ---- rs_new = r.r (direct reduction, R7 structure) ----
    float rn = rr * rr;
#pragma unroll
    for (int m = 32; m; m >>= 1) rn += __shfl_xor(rn, m, 64);
    if (lane == 0) red[8 + wid] = rn;
    __syncthreads();                             // bar 3
    float rsn = red[8 + 2 * h] + red[8 + 2 * h + 1];
    float beta = rsn / (rs + 1e-30f);
    rs = rsn;
    p = rr + beta * p;
    Pl[h][rB] = p;
    __syncthreads();                             // bar 4: P ready
  }

  // ---- epilogue: Pl <- z ; out = zeta(in out) + Qn z ----
  Pl[h][rB] = z;
  __syncthreads();
  float o0 = 0.f, o1 = 0.f;
#pragma unroll 8
  for (int gp = 0; gp < 32; ++gp) {
    float4 q = *reinterpret_cast<const float4*>(&Qs[nA * QSTRIDE + 4 * gp]);
    float4 za = PlA0[gp];
    float4 zb = PlA1[gp];
    o0 += q.x * za.x + q.y * za.y + q.z * za.z + q.w * za.w;
    o1 += q.x * zb.x + q.y * zb.y + q.z * zb.z + q.w * zb.w;
  }
  out[(bg0 + 2 * g2) * NN_ + nA] += o0;
  out[(bg0 + 2 * g2 + 1) * NN_ + nA] += o1;
}

// ---------------------------------------------------------------------------
extern "C" void kernel_launch(void* const* d_in, const int* in_sizes, int n_in,
                              void* d_out, int out_size, void* d_ws, size_t ws_size,
                              hipStream_t stream)
{
  const float* x     = (const float*)d_in[0];
  const float* parms = (const float*)d_in[1];
  // d_in[2] = A : unused (cancels algebraically)
  const float* Bp    = (const float*)d_in[3];
  const float* Qf    = (const float*)d_in[4];
  const float* Wf    = (const float*)d_in[5];
  const float* Qr    = (const float*)d_in[6];
  const float* Qn    = (const float*)d_in[7];
  const float* Rr    = (const float*)d_in[8];

  // Workspace: 245,760 floats = 0.94 MB (proven-safe region).
  float* ws   = (float*)d_ws;
  float* QfQn = ws;                 // [0      , 32768)
  float* WfQn = QfQn + 32768;       // [32768  , 40960)
  float* GT   = WfQn + 8192;        // [40960  , 73728)   GT[j][m] (256x128)
  float* H    = GT + 32768;         // [73728  , 90112)   H[p][n]  (64x256)
  float* Cm   = H + 16384;          // [90112  , 106496)  C (128x128)
  float* W2   = Cm + 16384;         // [106496 , 114688)  W2[p][r] (64x128)
  float* rhs  = W2 + 8192;          // [114688 , 245760)

  float* outp = (float*)d_out;

  hipLaunchKernelGGL(kA, dim3(224), dim3(256), 0, stream,
                     Qf, Qn, Wf, Qr, Rr, QfQn, WfQn, GT);
  hipLaunchKernelGGL(kB, dim3(80), dim3(256), 0, stream,
                     Qn, QfQn, Bp, GT, Cm, H);
  hipLaunchKernelGGL(kC, dim3(32), dim3(256), 0, stream,
                     H, QfQn, WfQn, W2);
  hipLaunchKernelGGL(k_vec, dim3(512), dim3(256), 0, stream,
                     x, parms, H, Qn, W2, outp, rhs);
  hipLaunchKernelGGL(k_cg, dim3(256), dim3(512), 0, stream,
                     x, Qn, Cm, rhs, outp);
}

// Round 10
// 198.622 us; speedup vs baseline: 5.2911x; 1.0843x over previous
//
#include <hip/hip_runtime.h>
#include <math.h>

#define BB_  1024
#define NN_  256
#define MM_  128
#define PP_  64
#define KKc  128   // N - M
#define CG_ITERS 13
#define QSTRIDE 132   // 128 cols + pad 4 (row base 528B = 33*16B -> b128-aligned)
#define WLDIM  268    // 256 + 4-per-64-chunk pad (bank-decorrelates rc groups)

// ---------------------------------------------------------------------------
// kA: QfQn = Qf@Qn (256x128) | WfQn[c][r] (64x128) |
//     GT[j][m] = (Rr^-1 Qr^T)[m][j]  via wave-per-column back-substitution
// ---------------------------------------------------------------------------
__global__ __launch_bounds__(256) void kA(
    const float* __restrict__ Qf, const float* __restrict__ Qn,
    const float* __restrict__ Wf, const float* __restrict__ Qr,
    const float* __restrict__ Rr,
    float* __restrict__ QfQn, float* __restrict__ WfQn,
    float* __restrict__ GT)
{
  __shared__ float smem[MM_ * 129];   // union across branches
  const int w = blockIdx.x, tid = threadIdx.x;
  if (w < 128) {
    float* arow = smem;               // [2][256]
    const int n0 = 2 * w;
    for (int idx = tid; idx < 2 * NN_; idx += 256)
      arow[idx] = Qf[(n0 + (idx >> 8)) * NN_ + (idx & 255)];
    __syncthreads();
    const int r = tid & 127, h = tid >> 7;
    float acc = 0.f;
    for (int m = 0; m < NN_; ++m) acc += arow[h * NN_ + m] * Qn[m * KKc + r];
    QfQn[(n0 + h) * KKc + r] = acc;
  } else if (w < 160) {
    float* wcol = smem;               // [2][256]
    const int c0 = 2 * (w - 128);
    for (int idx = tid; idx < 2 * NN_; idx += 256)
      wcol[idx] = Wf[(idx & 255) * PP_ + c0 + (idx >> 8)];
    __syncthreads();
    const int r = tid & 127, h = tid >> 7;
    float acc = 0.f;
    for (int n = 0; n < NN_; ++n) acc += wcol[h * NN_ + n] * Qn[n * KKc + r];
    WfQn[(c0 + h) * KKc + r] = acc;
  } else {
    // ---- G-solve: Rr (upper-tri) G[:,j] = Qr^T[:,j];  GT[j][:] = G[:,j] ----
    float* Rs = smem;                 // [128][129]
    for (int idx = tid; idx < MM_ * MM_; idx += 256)
      Rs[(idx >> 7) * 129 + (idx & 127)] = Rr[idx];
    __syncthreads();
    const int wv = tid >> 6, l = tid & 63;
    const int j = (w - 160) * 4 + wv;            // column 0..255
    float q0 = Qr[j * MM_ + l];                  // Qr^T[:,j] = Qr[j,:]
    float q1 = Qr[j * MM_ + 64 + l];
    float g0 = 0.f, g1 = 0.f;
    for (int k = MM_ - 1; k >= 0; --k) {
      float src = (k >= 64) ? q1 : q0;
      float num = __shfl(src, k & 63, 64);
      float gk = num / Rs[k * 129 + k];
      if (k >= 64) { if (l == k - 64) g1 = gk; }
      else         { if (l == k)     g0 = gk; }
      if (l < k)      q0 -= Rs[l * 129 + k] * gk;
      if (l + 64 < k) q1 -= Rs[(l + 64) * 129 + k] * gk;
    }
    GT[j * MM_ + l]      = g0;
    GT[j * MM_ + 64 + l] = g1;
  }
}

// ---------------------------------------------------------------------------
// kB: C = Qn.T @ QfQn (128x128) | H[p][j] = sum_m Bp[m][p] GT[j][m] (64x256)
// ---------------------------------------------------------------------------
__global__ __launch_bounds__(256) void kB(
    const float* __restrict__ Qn, const float* __restrict__ QfQn,
    const float* __restrict__ Bp, const float* __restrict__ GT,
    float* __restrict__ C, float* __restrict__ H)
{
  __shared__ float smem[MM_ * 65 + 16 * MM_];   // Bp[128][65] + GT rows [16][128]
  const int w = blockIdx.x, tid = threadIdx.x;
  if (w < 64) {
    float* qcol = smem;               // [2][256]
    const int r0 = 2 * w;
    for (int idx = tid; idx < 2 * NN_; idx += 256)
      qcol[idx] = Qn[(idx & 255) * KKc + r0 + (idx >> 8)];
    __syncthreads();
    const int s = tid & 127, h = tid >> 7;
    float acc = 0.f;
    for (int n = 0; n < NN_; ++n) acc += qcol[h * NN_ + n] * QfQn[n * KKc + s];
    C[(r0 + h) * KKc + s] = acc;
  } else {
    float* Bl = smem;                 // [128][65]
    float* Gl = smem + MM_ * 65;      // [16][128]
    const int j0 = (w - 64) * 16;
    for (int idx = tid; idx < MM_ * PP_; idx += 256)
      Bl[(idx >> 6) * 65 + (idx & 63)] = Bp[idx];
    for (int idx = tid; idx < 16 * MM_; idx += 256)
      Gl[idx] = GT[j0 * MM_ + idx];
    __syncthreads();
    const int p = tid & 63, jj = tid >> 6;
    for (int jl = jj; jl < 16; jl += 4) {
      float acc = 0.f;
      for (int m = 0; m < MM_; ++m) acc += Bl[m * 65 + p] * Gl[jl * MM_ + m];
      H[p * NN_ + j0 + jl] = acc;
    }
  }
}

// ---------------------------------------------------------------------------
// kC: W2[p][r] = sum_n H[p][n] QfQn[n][r] + WfQn[p][r]   (64x128)
// ---------------------------------------------------------------------------
__global__ __launch_bounds__(256) void kC(
    const float* __restrict__ H, const float* __restrict__ QfQn,
    const float* __restrict__ WfQn, float* __restrict__ W2)
{
  const int tid = threadIdx.x;
  const int p = blockIdx.x * 2 + (tid >> 7), r = tid & 127;
  float acc = WfQn[p * KKc + r];
  for (int n = 0; n < NN_; ++n) acc += H[p * NN_ + n] * QfQn[n * KKc + r];
  W2[p * KKc + r] = acc;
}

// ---------------------------------------------------------------------------
// k_vec: per batch (2/wg): zeta = parms@H -> OUT ; t = (1+x^2)(x - zeta)
//        rhs = t@Qn - parms@W2
// ---------------------------------------------------------------------------
__global__ __launch_bounds__(256) void k_vec(
    const float* __restrict__ x, const float* __restrict__ parms,
    const float* __restrict__ H, const float* __restrict__ Qn,
    const float* __restrict__ W2,
    float* __restrict__ out_zeta, float* __restrict__ rhs)
{
  const int b0 = blockIdx.x * 2, tid = threadIdx.x;
  __shared__ float pL[2][PP_], xL[2][NN_], tL[2][NN_];
  for (int idx = tid; idx < 2 * PP_; idx += 256)
    pL[idx >> 6][idx & 63] = parms[(b0 + (idx >> 6)) * PP_ + (idx & 63)];
  for (int idx = tid; idx < 2 * NN_; idx += 256)
    xL[idx >> 8][idx & 255] = x[(b0 + (idx >> 8)) * NN_ + (idx & 255)];
  __syncthreads();
  {
    const int n = tid;
    float a0 = 0.f, a1 = 0.f;
    for (int p = 0; p < PP_; ++p) {
      float hv = H[p * NN_ + n];
      a0 += pL[0][p] * hv;
      a1 += pL[1][p] * hv;
    }
    float x0 = xL[0][n], x1 = xL[1][n];
    tL[0][n] = (1.f + x0 * x0) * (x0 - a0);
    tL[1][n] = (1.f + x1 * x1) * (x1 - a1);
    out_zeta[b0 * NN_ + n] = a0;
    out_zeta[(b0 + 1) * NN_ + n] = a1;
  }
  __syncthreads();
  {
    const int r = tid & 127, h = tid >> 7;
    float acc = 0.f;
    for (int n = 0; n < NN_; ++n) acc += tL[h][n] * Qn[n * KKc + r];
    for (int p = 0; p < PP_; ++p) acc -= pL[h][p] * W2[p * KKc + r];
    rhs[(b0 + h) * KKc + r] = acc;
  }
}

// ---------------------------------------------------------------------------
// k_cg (v6 = R9 + quad-axpy role B): 4 batches/wg, 512 threads.
//  Role B v = QnT W rewritten: lane=(cg=lane&15, rc=lane>>4) accumulates a
//  float4 col-slice [cbase+4cg..+3] over rows rc*64..+63 via ds_read_b128
//  (quarter-phase conflict-free), Wl padded +4/chunk (distinct banks per rc),
//  then butterfly over rc (shfl_xor 16,32) + bpermute redistribution.
//  LDS insts/wave/iter: 643 -> ~263. Reductions/barriers: R9 verbatim.
// ---------------------------------------------------------------------------
__global__ __launch_bounds__(512, 2) void k_cg(
    const float* __restrict__ x, const float* __restrict__ Qn,
    const float* __restrict__ C, const float* __restrict__ rhs,
    float* __restrict__ out)
{
  const int tid = threadIdx.x;
  const int nA = tid & 255, g2 = tid >> 8;       // role A: batches 2g2, 2g2+1
  const int rB = tid & 127, h = tid >> 7;        // role B: batch h
  const int wid = tid >> 6, lane = tid & 63;
  const int bg0 = blockIdx.x * 4;

  __shared__ __align__(16) float Qs[NN_ * QSTRIDE];
  __shared__ __align__(16) float Pl[4][KKc];
  __shared__ __align__(16) float Wl[4][WLDIM];
  __shared__ float red[16];

  // ---- stage Qn -> LDS [256][132] with b128 writes ----
  for (int j = 0; j < 16; ++j) {
    int f4 = j * 512 + tid;
    int n = f4 >> 5, g = f4 & 31;
    float4 v = reinterpret_cast<const float4*>(Qn)[f4];
    *reinterpret_cast<float4*>(&Qs[n * QSTRIDE + 4 * g]) = v;
  }

  // ---- hoist C row rB into registers: (C.p)[rB] = row(rB) . p ----
  float4 creg[32];
#pragma unroll
  for (int j = 0; j < 32; ++j)
    creg[j] = reinterpret_cast<const float4*>(C)[rB * 32 + j];

  // ---- role-A constants ----
  float xa0 = x[(bg0 + 2 * g2) * NN_ + nA];
  float xa1 = x[(bg0 + 2 * g2 + 1) * NN_ + nA];
  const float dA0 = 1.f + xa0 * xa0;
  const float dA1 = 1.f + xa1 * xa1;
  const int nAp = nA + 4 * (nA >> 6);            // padded Wl index for row nA

  // ---- role-B quad-axpy constants ----
  const int cbase = rB & 64;                     // wave's 64-col base
  const int cg = lane & 15, rc = lane >> 4;
  const int n0q = rc * 64;                       // this lane's row chunk
  const int srcl = (lane & 48) | (lane >> 2);    // redistribution source lane
  const int e = lane & 3;                        // component select

  // ---- role-B init: p = r = rhs ----
  float rr = rhs[(bg0 + h) * KKc + rB];
  float p = rr, z = 0.f;
  Pl[h][rB] = p;

  float t = rr * rr;
#pragma unroll
  for (int m = 32; m; m >>= 1) t += __shfl_xor(t, m, 64);
  if (lane == 0) red[wid] = t;
  __syncthreads();
  float rs = red[2 * h] + red[2 * h + 1];

  const float4* PlA0 = reinterpret_cast<const float4*>(Pl[2 * g2]);
  const float4* PlA1 = reinterpret_cast<const float4*>(Pl[2 * g2 + 1]);
  const float4* PlB  = reinterpret_cast<const float4*>(Pl[h]);

  for (int it = 0; it < CG_ITERS; ++it) {
    // ---- role A: u = Qn p (b128 row reads + float4 P broadcast) ----
    float u0 = 0.f, u1 = 0.f;
#pragma unroll 8
    for (int gp = 0; gp < 32; ++gp) {
      float4 q = *reinterpret_cast<const float4*>(&Qs[nA * QSTRIDE + 4 * gp]);
      float4 pa = PlA0[gp];
      float4 pb = PlA1[gp];
      u0 += q.x * pa.x + q.y * pa.y + q.z * pa.z + q.w * pa.w;
      u1 += q.x * pb.x + q.y * pb.y + q.z * pb.z + q.w * pb.w;
    }
    Wl[2 * g2][nAp] = dA0 * u0;
    Wl[2 * g2 + 1][nAp] = dA1 * u1;
    __syncthreads();                             // bar 1: W ready

    // ---- role B: v = QnT W via quad-axpy (b128 rows, butterfly, bpermute) ----
    float4 v4 = {0.f, 0.f, 0.f, 0.f};
#pragma unroll 8
    for (int j = 0; j < 64; ++j) {
      int n = n0q + j;
      float wv = Wl[h][n + 4 * rc];
      float4 q = *reinterpret_cast<const float4*>(&Qs[n * QSTRIDE + cbase + 4 * cg]);
      v4.x += wv * q.x; v4.y += wv * q.y; v4.z += wv * q.z; v4.w += wv * q.w;
    }
    v4.x += __shfl_xor(v4.x, 16, 64); v4.y += __shfl_xor(v4.y, 16, 64);
    v4.z += __shfl_xor(v4.z, 16, 64); v4.w += __shfl_xor(v4.w, 16, 64);
    v4.x += __shfl_xor(v4.x, 32, 64); v4.y += __shfl_xor(v4.y, 32, 64);
    v4.z += __shfl_xor(v4.z, 32, 64); v4.w += __shfl_xor(v4.w, 32, 64);
    float vsx = __shfl(v4.x, srcl, 64), vsy = __shfl(v4.y, srcl, 64);
    float vsz = __shfl(v4.z, srcl, 64), vsw = __shfl(v4.w, srcl, 64);
    float v = (e == 0) ? vsx : (e == 1) ? vsy : (e == 2) ? vsz : vsw;

    // ---- + C p (registers) ----
#pragma unroll
    for (int j = 0; j < 32; ++j) {
      float4 p4 = PlB[j];
      float4 c4 = creg[j];
      v += c4.x * p4.x + c4.y * p4.y + c4.z * p4.z + c4.w * p4.w;
    }

    // ---- pv reduction (R9 structure) ----
    float pv = p * v;
#pragma unroll
    for (int m = 32; m; m >>= 1) pv += __shfl_xor(pv, m, 64);
    if (lane == 0) red[wid] = pv;
    __syncthreads();                             // bar 2
    float pvb = red[2 * h] + red[2 * h + 1];
    float alpha = rs / (pvb + 1e-30f);
    z += alpha * p;
    rr -= alpha * v;

    // ---- rs_new = r.r (direct reduction, R9 structure) ----
    float rn = rr * rr;
#pragma unroll
    for (int m = 32; m; m >>= 1) rn += __shfl_xor(rn, m, 64);
    if (lane == 0) red[8 + wid] = rn;
    __syncthreads();                             // bar 3
    float rsn = red[8 + 2 * h] + red[8 + 2 * h + 1];
    float beta = rsn / (rs + 1e-30f);
    rs = rsn;
    p = rr + beta * p;
    Pl[h][rB] = p;
    __syncthreads();                             // bar 4: P ready
  }

  // ---- epilogue: Pl <- z ; out = zeta(in out) + Qn z ----
  Pl[h][rB] = z;
  __syncthreads();
  float o0 = 0.f, o1 = 0.f;
#pragma unroll 8
  for (int gp = 0; gp < 32; ++gp) {
    float4 q = *reinterpret_cast<const float4*>(&Qs[nA * QSTRIDE + 4 * gp]);
    float4 za = PlA0[gp];
    float4 zb = PlA1[gp];
    o0 += q.x * za.x + q.y * za.y + q.z * za.z + q.w * za.w;
    o1 += q.x * zb.x + q.y * zb.y + q.z * zb.z + q.w * zb.w;
  }
  out[(bg0 + 2 * g2) * NN_ + nA] += o0;
  out[(bg0 + 2 * g2 + 1) * NN_ + nA] += o1;
}

// ---------------------------------------------------------------------------
extern "C" void kernel_launch(void* const* d_in, const int* in_sizes, int n_in,
                              void* d_out, int out_size, void* d_ws, size_t ws_size,
                              hipStream_t stream)
{
  const float* x     = (const float*)d_in[0];
  const float* parms = (const float*)d_in[1];
  // d_in[2] = A : unused (cancels algebraically)
  const float* Bp    = (const float*)d_in[3];
  const float* Qf    = (const float*)d_in[4];
  const float* Wf    = (const float*)d_in[5];
  const float* Qr    = (const float*)d_in[6];
  const float* Qn    = (const float*)d_in[7];
  const float* Rr    = (const float*)d_in[8];

  // Workspace: 245,760 floats = 0.94 MB (proven-safe region).
  float* ws   = (float*)d_ws;
  float* QfQn = ws;                 // [0      , 32768)
  float* WfQn = QfQn + 32768;       // [32768  , 40960)
  float* GT   = WfQn + 8192;        // [40960  , 73728)   GT[j][m] (256x128)
  float* H    = GT + 32768;         // [73728  , 90112)   H[p][n]  (64x256)
  float* Cm   = H + 16384;          // [90112  , 106496)  C (128x128)
  float* W2   = Cm + 16384;         // [106496 , 114688)  W2[p][r] (64x128)
  float* rhs  = W2 + 8192;          // [114688 , 245760)

  float* outp = (float*)d_out;

  hipLaunchKernelGGL(kA, dim3(224), dim3(256), 0, stream,
                     Qf, Qn, Wf, Qr, Rr, QfQn, WfQn, GT);
  hipLaunchKernelGGL(kB, dim3(80), dim3(256), 0, stream,
                     Qn, QfQn, Bp, GT, Cm, H);
  hipLaunchKernelGGL(kC, dim3(32), dim3(256), 0, stream,
                     H, QfQn, WfQn, W2);
  hipLaunchKernelGGL(k_vec, dim3(512), dim3(256), 0, stream,
                     x, parms, H, Qn, W2, outp, rhs);
  hipLaunchKernelGGL(k_cg, dim3(256), dim3(512), 0, stream,
                     x, Qn, Cm, rhs, outp);
}

// Round 11
// 193.323 us; speedup vs baseline: 5.4362x; 1.0274x over previous
//
#include <hip/hip_runtime.h>
#include <math.h>

#define BB_  1024
#define NN_  256
#define MM_  128
#define PP_  64
#define KKc  128   // N - M
#define CG_ITERS 12
#define QSTRIDE 132   // 128 cols + pad 4 (row base 528B = 33*16B -> b128-aligned)
#define WLDIM  268    // 4 chunks of 68 floats (64 data + 4 pad) -> rc groups on disjoint banks

// ---------------------------------------------------------------------------
// kA: QfQn = Qf@Qn (256x128) | WfQn[c][r] (64x128) |
//     GT[j][m] = (Rr^-1 Qr^T)[m][j]  via wave-per-column back-substitution
// ---------------------------------------------------------------------------
__global__ __launch_bounds__(256) void kA(
    const float* __restrict__ Qf, const float* __restrict__ Qn,
    const float* __restrict__ Wf, const float* __restrict__ Qr,
    const float* __restrict__ Rr,
    float* __restrict__ QfQn, float* __restrict__ WfQn,
    float* __restrict__ GT)
{
  __shared__ float smem[MM_ * 129];   // union across branches
  const int w = blockIdx.x, tid = threadIdx.x;
  if (w < 128) {
    float* arow = smem;               // [2][256]
    const int n0 = 2 * w;
    for (int idx = tid; idx < 2 * NN_; idx += 256)
      arow[idx] = Qf[(n0 + (idx >> 8)) * NN_ + (idx & 255)];
    __syncthreads();
    const int r = tid & 127, h = tid >> 7;
    float acc = 0.f;
    for (int m = 0; m < NN_; ++m) acc += arow[h * NN_ + m] * Qn[m * KKc + r];
    QfQn[(n0 + h) * KKc + r] = acc;
  } else if (w < 160) {
    float* wcol = smem;               // [2][256]
    const int c0 = 2 * (w - 128);
    for (int idx = tid; idx < 2 * NN_; idx += 256)
      wcol[idx] = Wf[(idx & 255) * PP_ + c0 + (idx >> 8)];
    __syncthreads();
    const int r = tid & 127, h = tid >> 7;
    float acc = 0.f;
    for (int n = 0; n < NN_; ++n) acc += wcol[h * NN_ + n] * Qn[n * KKc + r];
    WfQn[(c0 + h) * KKc + r] = acc;
  } else {
    // ---- G-solve: Rr (upper-tri) G[:,j] = Qr^T[:,j];  GT[j][:] = G[:,j] ----
    float* Rs = smem;                 // [128][129]
    for (int idx = tid; idx < MM_ * MM_; idx += 256)
      Rs[(idx >> 7) * 129 + (idx & 127)] = Rr[idx];
    __syncthreads();
    const int wv = tid >> 6, l = tid & 63;
    const int j = (w - 160) * 4 + wv;            // column 0..255
    float q0 = Qr[j * MM_ + l];                  // Qr^T[:,j] = Qr[j,:]
    float q1 = Qr[j * MM_ + 64 + l];
    float g0 = 0.f, g1 = 0.f;
    for (int k = MM_ - 1; k >= 0; --k) {
      float src = (k >= 64) ? q1 : q0;
      float num = __shfl(src, k & 63, 64);
      float gk = num / Rs[k * 129 + k];
      if (k >= 64) { if (l == k - 64) g1 = gk; }
      else         { if (l == k)     g0 = gk; }
      if (l < k)      q0 -= Rs[l * 129 + k] * gk;
      if (l + 64 < k) q1 -= Rs[(l + 64) * 129 + k] * gk;
    }
    GT[j * MM_ + l]      = g0;
    GT[j * MM_ + 64 + l] = g1;
  }
}

// ---------------------------------------------------------------------------
// kB: C = Qn.T @ QfQn (128x128) | H[p][j] = sum_m Bp[m][p] GT[j][m] (64x256)
// ---------------------------------------------------------------------------
__global__ __launch_bounds__(256) void kB(
    const float* __restrict__ Qn, const float* __restrict__ QfQn,
    const float* __restrict__ Bp, const float* __restrict__ GT,
    float* __restrict__ C, float* __restrict__ H)
{
  __shared__ float smem[MM_ * 65 + 16 * MM_];   // Bp[128][65] + GT rows [16][128]
  const int w = blockIdx.x, tid = threadIdx.x;
  if (w < 64) {
    float* qcol = smem;               // [2][256]
    const int r0 = 2 * w;
    for (int idx = tid; idx < 2 * NN_; idx += 256)
      qcol[idx] = Qn[(idx & 255) * KKc + r0 + (idx >> 8)];
    __syncthreads();
    const int s = tid & 127, h = tid >> 7;
    float acc = 0.f;
    for (int n = 0; n < NN_; ++n) acc += qcol[h * NN_ + n] * QfQn[n * KKc + s];
    C[(r0 + h) * KKc + s] = acc;
  } else {
    float* Bl = smem;                 // [128][65]
    float* Gl = smem + MM_ * 65;      // [16][128]
    const int j0 = (w - 64) * 16;
    for (int idx = tid; idx < MM_ * PP_; idx += 256)
      Bl[(idx >> 6) * 65 + (idx & 63)] = Bp[idx];
    for (int idx = tid; idx < 16 * MM_; idx += 256)
      Gl[idx] = GT[j0 * MM_ + idx];
    __syncthreads();
    const int p = tid & 63, jj = tid >> 6;
    for (int jl = jj; jl < 16; jl += 4) {
      float acc = 0.f;
      for (int m = 0; m < MM_; ++m) acc += Bl[m * 65 + p] * Gl[jl * MM_ + m];
      H[p * NN_ + j0 + jl] = acc;
    }
  }
}

// ---------------------------------------------------------------------------
// kC: W2[p][r] = sum_n H[p][n] QfQn[n][r] + WfQn[p][r]   (64x128)
// ---------------------------------------------------------------------------
__global__ __launch_bounds__(256) void kC(
    const float* __restrict__ H, const float* __restrict__ QfQn,
    const float* __restrict__ WfQn, float* __restrict__ W2)
{
  const int tid = threadIdx.x;
  const int p = blockIdx.x * 2 + (tid >> 7), r = tid & 127;
  float acc = WfQn[p * KKc + r];
  for (int n = 0; n < NN_; ++n) acc += H[p * NN_ + n] * QfQn[n * KKc + r];
  W2[p * KKc + r] = acc;
}

// ---------------------------------------------------------------------------
// k_cg (v7 = R10 + k_vec fusion + b128 Wl reads + 12 iters):
//  Prologue (fused k_vec): zeta = parms@H -> zL (LDS); t = (1+x^2)(x-zeta)
//  -> Wl; rhs = Qn^T t - parms@W2 via the proven quad-axpy+butterfly path.
//  CG loop: R10 math bit-identical; role-B Wl reads 64-scalar -> 16 b128
//  (chunk pad 68 floats puts the 4 rc-group addresses on disjoint banks).
//  Epilogue: out = zL + Qn z  (single write, no global read of out).
// ---------------------------------------------------------------------------
__global__ __launch_bounds__(512, 2) void k_cg(
    const float* __restrict__ x, const float* __restrict__ Qn,
    const float* __restrict__ C, const float* __restrict__ parms,
    const float* __restrict__ H, const float* __restrict__ W2,
    float* __restrict__ out)
{
  const int tid = threadIdx.x;
  const int nA = tid & 255, g2 = tid >> 8;       // role A: batches 2g2, 2g2+1
  const int rB = tid & 127, h = tid >> 7;        // role B: batch h
  const int wid = tid >> 6, lane = tid & 63;
  const int bg0 = blockIdx.x * 4;

  __shared__ __align__(16) float Qs[NN_ * QSTRIDE];
  __shared__ __align__(16) float Pl[4][KKc];
  __shared__ __align__(16) float Wl[4][WLDIM];
  __shared__ __align__(16) float zL[4][NN_];
  __shared__ float red[16];

  // ---- stage Qn -> LDS [256][132] with b128 writes ----
  for (int j = 0; j < 16; ++j) {
    int f4 = j * 512 + tid;
    int n = f4 >> 5, g = f4 & 31;
    float4 v = reinterpret_cast<const float4*>(Qn)[f4];
    *reinterpret_cast<float4*>(&Qs[n * QSTRIDE + 4 * g]) = v;
  }

  // ---- hoist C row rB: (C.p)[rB] = row(rB) . p ----
  float4 creg[32];
#pragma unroll
  for (int j = 0; j < 32; ++j)
    creg[j] = reinterpret_cast<const float4*>(C)[rB * 32 + j];

  // ---- role-A constants ----
  const int b0A = bg0 + 2 * g2, b1A = b0A + 1;
  float xa0 = x[b0A * NN_ + nA];
  float xa1 = x[b1A * NN_ + nA];
  const float dA0 = 1.f + xa0 * xa0;
  const float dA1 = 1.f + xa1 * xa1;
  const int nAp = nA + 4 * (nA >> 6);            // padded Wl index for row nA

  // ---- role-B quad-axpy constants ----
  const int cbase = rB & 64;                     // wave's 64-col base
  const int cg = lane & 15, rc = lane >> 4;
  const int n0q = rc * 64;                       // this lane's row chunk
  const int wbase = 68 * rc;                     // padded Wl chunk base
  const int srcl = (lane & 48) | (lane >> 2);    // redistribution source lane
  const int e = lane & 3;                        // component select

  // ================= PROLOGUE (fused k_vec) =================
  // role A: zeta, t for 2 batches at row nA
  {
    float za0 = 0.f, za1 = 0.f;
    for (int p = 0; p < PP_; ++p) {
      float hv = H[p * NN_ + nA];                // coalesced; parms wave-uniform
      za0 += parms[b0A * PP_ + p] * hv;
      za1 += parms[b1A * PP_ + p] * hv;
    }
    zL[2 * g2][nA] = za0;
    zL[2 * g2 + 1][nA] = za1;
    Wl[2 * g2][nAp] = dA0 * (xa0 - za0);         // t
    Wl[2 * g2 + 1][nAp] = dA1 * (xa1 - za1);
  }
  __syncthreads();

  // role B: rhs[rB] = (Qn^T t)[rB] - (parms @ W2)[rB]  (batch h)
  float rr;
  {
    float4 v4 = {0.f, 0.f, 0.f, 0.f};
#pragma unroll 4
    for (int j4 = 0; j4 < 16; ++j4) {
      float4 w4 = *reinterpret_cast<const float4*>(&Wl[h][wbase + 4 * j4]);
      int n = n0q + 4 * j4;
      float4 q0 = *reinterpret_cast<const float4*>(&Qs[(n + 0) * QSTRIDE + cbase + 4 * cg]);
      float4 q1 = *reinterpret_cast<const float4*>(&Qs[(n + 1) * QSTRIDE + cbase + 4 * cg]);
      float4 q2 = *reinterpret_cast<const float4*>(&Qs[(n + 2) * QSTRIDE + cbase + 4 * cg]);
      float4 q3 = *reinterpret_cast<const float4*>(&Qs[(n + 3) * QSTRIDE + cbase + 4 * cg]);
      v4.x += w4.x * q0.x + w4.y * q1.x + w4.z * q2.x + w4.w * q3.x;
      v4.y += w4.x * q0.y + w4.y * q1.y + w4.z * q2.y + w4.w * q3.y;
      v4.z += w4.x * q0.z + w4.y * q1.z + w4.z * q2.z + w4.w * q3.z;
      v4.w += w4.x * q0.w + w4.y * q1.w + w4.z * q2.w + w4.w * q3.w;
    }
    v4.x += __shfl_xor(v4.x, 16, 64); v4.y += __shfl_xor(v4.y, 16, 64);
    v4.z += __shfl_xor(v4.z, 16, 64); v4.w += __shfl_xor(v4.w, 16, 64);
    v4.x += __shfl_xor(v4.x, 32, 64); v4.y += __shfl_xor(v4.y, 32, 64);
    v4.z += __shfl_xor(v4.z, 32, 64); v4.w += __shfl_xor(v4.w, 32, 64);
    float vsx = __shfl(v4.x, srcl, 64), vsy = __shfl(v4.y, srcl, 64);
    float vsz = __shfl(v4.z, srcl, 64), vsw = __shfl(v4.w, srcl, 64);
    rr = (e == 0) ? vsx : (e == 1) ? vsy : (e == 2) ? vsz : vsw;
    for (int p = 0; p < PP_; ++p)
      rr -= parms[(bg0 + h) * PP_ + p] * W2[p * KKc + rB];
  }

  // ---- CG init ----
  float p = rr, z = 0.f;
  Pl[h][rB] = p;
  float t0r = rr * rr;
#pragma unroll
  for (int m = 32; m; m >>= 1) t0r += __shfl_xor(t0r, m, 64);
  if (lane == 0) red[wid] = t0r;
  __syncthreads();
  float rs = red[2 * h] + red[2 * h + 1];

  const float4* PlA0 = reinterpret_cast<const float4*>(Pl[2 * g2]);
  const float4* PlA1 = reinterpret_cast<const float4*>(Pl[2 * g2 + 1]);
  const float4* PlB  = reinterpret_cast<const float4*>(Pl[h]);

  for (int it = 0; it < CG_ITERS; ++it) {
    // ---- role A: u = Qn p (b128 row reads + float4 P broadcast) ----
    float u0 = 0.f, u1 = 0.f;
#pragma unroll 8
    for (int gp = 0; gp < 32; ++gp) {
      float4 q = *reinterpret_cast<const float4*>(&Qs[nA * QSTRIDE + 4 * gp]);
      float4 pa = PlA0[gp];
      float4 pb = PlA1[gp];
      u0 += q.x * pa.x + q.y * pa.y + q.z * pa.z + q.w * pa.w;
      u1 += q.x * pb.x + q.y * pb.y + q.z * pb.z + q.w * pb.w;
    }
    Wl[2 * g2][nAp] = dA0 * u0;
    Wl[2 * g2 + 1][nAp] = dA1 * u1;
    __syncthreads();                             // bar 1: W ready

    // ---- role B: v = QnT W via quad-axpy (b128 Qs + b128 Wl) ----
    float4 v4 = {0.f, 0.f, 0.f, 0.f};
#pragma unroll 4
    for (int j4 = 0; j4 < 16; ++j4) {
      float4 w4 = *reinterpret_cast<const float4*>(&Wl[h][wbase + 4 * j4]);
      int n = n0q + 4 * j4;
      float4 q0 = *reinterpret_cast<const float4*>(&Qs[(n + 0) * QSTRIDE + cbase + 4 * cg]);
      float4 q1 = *reinterpret_cast<const float4*>(&Qs[(n + 1) * QSTRIDE + cbase + 4 * cg]);
      float4 q2 = *reinterpret_cast<const float4*>(&Qs[(n + 2) * QSTRIDE + cbase + 4 * cg]);
      float4 q3 = *reinterpret_cast<const float4*>(&Qs[(n + 3) * QSTRIDE + cbase + 4 * cg]);
      v4.x += w4.x * q0.x + w4.y * q1.x + w4.z * q2.x + w4.w * q3.x;
      v4.y += w4.x * q0.y + w4.y * q1.y + w4.z * q2.y + w4.w * q3.y;
      v4.z += w4.x * q0.z + w4.y * q1.z + w4.z * q2.z + w4.w * q3.z;
      v4.w += w4.x * q0.w + w4.y * q1.w + w4.z * q2.w + w4.w * q3.w;
    }
    v4.x += __shfl_xor(v4.x, 16, 64); v4.y += __shfl_xor(v4.y, 16, 64);
    v4.z += __shfl_xor(v4.z, 16, 64); v4.w += __shfl_xor(v4.w, 16, 64);
    v4.x += __shfl_xor(v4.x, 32, 64); v4.y += __shfl_xor(v4.y, 32, 64);
    v4.z += __shfl_xor(v4.z, 32, 64); v4.w += __shfl_xor(v4.w, 32, 64);
    float vsx = __shfl(v4.x, srcl, 64), vsy = __shfl(v4.y, srcl, 64);
    float vsz = __shfl(v4.z, srcl, 64), vsw = __shfl(v4.w, srcl, 64);
    float v = (e == 0) ? vsx : (e == 1) ? vsy : (e == 2) ? vsz : vsw;

    // ---- + C p (creg) ----
#pragma unroll
    for (int j = 0; j < 32; ++j) {
      float4 p4 = PlB[j];
      float4 c4 = creg[j];
      v += c4.x * p4.x + c4.y * p4.y + c4.z * p4.z + c4.w * p4.w;
    }

    // ---- pv reduction ----
    float pv = p * v;
#pragma unroll
    for (int m = 32; m; m >>= 1) pv += __shfl_xor(pv, m, 64);
    if (lane == 0) red[wid] = pv;
    __syncthreads();                             // bar 2
    float pvb = red[2 * h] + red[2 * h + 1];
    float alpha = rs / (pvb + 1e-30f);
    z += alpha * p;
    rr -= alpha * v;

    // ---- rs_new = r.r (direct reduction) ----
    float rn = rr * rr;
#pragma unroll
    for (int m = 32; m; m >>= 1) rn += __shfl_xor(rn, m, 64);
    if (lane == 0) red[8 + wid] = rn;
    __syncthreads();                             // bar 3
    float rsn = red[8 + 2 * h] + red[8 + 2 * h + 1];
    float beta = rsn / (rs + 1e-30f);
    rs = rsn;
    p = rr + beta * p;
    Pl[h][rB] = p;
    __syncthreads();                             // bar 4: P ready
  }

  // ---- epilogue: Pl <- z ; out = zL + Qn z (single write) ----
  Pl[h][rB] = z;
  __syncthreads();
  float o0 = zL[2 * g2][nA], o1 = zL[2 * g2 + 1][nA];
#pragma unroll 8
  for (int gp = 0; gp < 32; ++gp) {
    float4 q = *reinterpret_cast<const float4*>(&Qs[nA * QSTRIDE + 4 * gp]);
    float4 za = PlA0[gp];
    float4 zb = PlA1[gp];
    o0 += q.x * za.x + q.y * za.y + q.z * za.z + q.w * za.w;
    o1 += q.x * zb.x + q.y * zb.y + q.z * zb.z + q.w * zb.w;
  }
  out[b0A * NN_ + nA] = o0;
  out[b1A * NN_ + nA] = o1;
}

// ---------------------------------------------------------------------------
extern "C" void kernel_launch(void* const* d_in, const int* in_sizes, int n_in,
                              void* d_out, int out_size, void* d_ws, size_t ws_size,
                              hipStream_t stream)
{
  const float* x     = (const float*)d_in[0];
  const float* parms = (const float*)d_in[1];
  // d_in[2] = A : unused (cancels algebraically)
  const float* Bp    = (const float*)d_in[3];
  const float* Qf    = (const float*)d_in[4];
  const float* Wf    = (const float*)d_in[5];
  const float* Qr    = (const float*)d_in[6];
  const float* Qn    = (const float*)d_in[7];
  const float* Rr    = (const float*)d_in[8];

  // Workspace: 114,688 floats = 0.44 MB (proven-safe region).
  float* ws   = (float*)d_ws;
  float* QfQn = ws;                 // [0      , 32768)
  float* WfQn = QfQn + 32768;       // [32768  , 40960)
  float* GT   = WfQn + 8192;        // [40960  , 73728)   GT[j][m] (256x128)
  float* H    = GT + 32768;         // [73728  , 90112)   H[p][n]  (64x256)
  float* Cm   = H + 16384;          // [90112  , 106496)  C (128x128)
  float* W2   = Cm + 16384;         // [106496 , 114688)  W2[p][r] (64x128)

  float* outp = (float*)d_out;

  hipLaunchKernelGGL(kA, dim3(224), dim3(256), 0, stream,
                     Qf, Qn, Wf, Qr, Rr, QfQn, WfQn, GT);
  hipLaunchKernelGGL(kB, dim3(80), dim3(256), 0, stream,
                     Qn, QfQn, Bp, GT, Cm, H);
  hipLaunchKernelGGL(kC, dim3(32), dim3(256), 0, stream,
                     H, QfQn, WfQn, W2);
  hipLaunchKernelGGL(k_cg, dim3(256), dim3(512), 0, stream,
                     x, Qn, Cm, parms, H, W2, outp);
}

// Round 12
// 177.590 us; speedup vs baseline: 5.9178x; 1.0886x over previous
//
#include <hip/hip_runtime.h>
#include <math.h>

#define BB_  1024
#define NN_  256
#define MM_  128
#define PP_  64
#define KKc  128   // N - M
#define CG_ITERS 10
#define QSTRIDE 132   // 128 cols + pad 4 (row base 528B = 33*16B -> b128-aligned)
#define WLDIM  268    // 4 chunks of 68 floats (64 data + 4 pad) -> rc groups on disjoint banks

// ---------------------------------------------------------------------------
// kA: QfQn = Qf@Qn (256x128) | WfQn[c][r] (64x128) |
//     GT[j][m] = (Rr^-1 Qr^T)[m][j]  via wave-per-column back-substitution
// ---------------------------------------------------------------------------
__global__ __launch_bounds__(256) void kA(
    const float* __restrict__ Qf, const float* __restrict__ Qn,
    const float* __restrict__ Wf, const float* __restrict__ Qr,
    const float* __restrict__ Rr,
    float* __restrict__ QfQn, float* __restrict__ WfQn,
    float* __restrict__ GT)
{
  __shared__ float smem[MM_ * 129];   // union across branches
  const int w = blockIdx.x, tid = threadIdx.x;
  if (w < 128) {
    float* arow = smem;               // [2][256]
    const int n0 = 2 * w;
    for (int idx = tid; idx < 2 * NN_; idx += 256)
      arow[idx] = Qf[(n0 + (idx >> 8)) * NN_ + (idx & 255)];
    __syncthreads();
    const int r = tid & 127, h = tid >> 7;
    float acc = 0.f;
    for (int m = 0; m < NN_; ++m) acc += arow[h * NN_ + m] * Qn[m * KKc + r];
    QfQn[(n0 + h) * KKc + r] = acc;
  } else if (w < 160) {
    float* wcol = smem;               // [2][256]
    const int c0 = 2 * (w - 128);
    for (int idx = tid; idx < 2 * NN_; idx += 256)
      wcol[idx] = Wf[(idx & 255) * PP_ + c0 + (idx >> 8)];
    __syncthreads();
    const int r = tid & 127, h = tid >> 7;
    float acc = 0.f;
    for (int n = 0; n < NN_; ++n) acc += wcol[h * NN_ + n] * Qn[n * KKc + r];
    WfQn[(c0 + h) * KKc + r] = acc;
  } else {
    // ---- G-solve: Rr (upper-tri) G[:,j] = Qr^T[:,j];  GT[j][:] = G[:,j] ----
    float* Rs = smem;                 // [128][129]
    for (int idx = tid; idx < MM_ * MM_; idx += 256)
      Rs[(idx >> 7) * 129 + (idx & 127)] = Rr[idx];
    __syncthreads();
    const int wv = tid >> 6, l = tid & 63;
    const int j = (w - 160) * 4 + wv;            // column 0..255
    float q0 = Qr[j * MM_ + l];                  // Qr^T[:,j] = Qr[j,:]
    float q1 = Qr[j * MM_ + 64 + l];
    float g0 = 0.f, g1 = 0.f;
    for (int k = MM_ - 1; k >= 0; --k) {
      float src = (k >= 64) ? q1 : q0;
      float num = __shfl(src, k & 63, 64);
      float gk = num / Rs[k * 129 + k];
      if (k >= 64) { if (l == k - 64) g1 = gk; }
      else         { if (l == k)     g0 = gk; }
      if (l < k)      q0 -= Rs[l * 129 + k] * gk;
      if (l + 64 < k) q1 -= Rs[(l + 64) * 129 + k] * gk;
    }
    GT[j * MM_ + l]      = g0;
    GT[j * MM_ + 64 + l] = g1;
  }
}

// ---------------------------------------------------------------------------
// kB: C = Qn.T @ QfQn (128x128) | H[p][j] = sum_m Bp[m][p] GT[j][m] (64x256)
// ---------------------------------------------------------------------------
__global__ __launch_bounds__(256) void kB(
    const float* __restrict__ Qn, const float* __restrict__ QfQn,
    const float* __restrict__ Bp, const float* __restrict__ GT,
    float* __restrict__ C, float* __restrict__ H)
{
  __shared__ float smem[MM_ * 65 + 16 * MM_];   // Bp[128][65] + GT rows [16][128]
  const int w = blockIdx.x, tid = threadIdx.x;
  if (w < 64) {
    float* qcol = smem;               // [2][256]
    const int r0 = 2 * w;
    for (int idx = tid; idx < 2 * NN_; idx += 256)
      qcol[idx] = Qn[(idx & 255) * KKc + r0 + (idx >> 8)];
    __syncthreads();
    const int s = tid & 127, h = tid >> 7;
    float acc = 0.f;
    for (int n = 0; n < NN_; ++n) acc += qcol[h * NN_ + n] * QfQn[n * KKc + s];
    C[(r0 + h) * KKc + s] = acc;
  } else {
    float* Bl = smem;                 // [128][65]
    float* Gl = smem + MM_ * 65;      // [16][128]
    const int j0 = (w - 64) * 16;
    for (int idx = tid; idx < MM_ * PP_; idx += 256)
      Bl[(idx >> 6) * 65 + (idx & 63)] = Bp[idx];
    for (int idx = tid; idx < 16 * MM_; idx += 256)
      Gl[idx] = GT[j0 * MM_ + idx];
    __syncthreads();
    const int p = tid & 63, jj = tid >> 6;
    for (int jl = jj; jl < 16; jl += 4) {
      float acc = 0.f;
      for (int m = 0; m < MM_; ++m) acc += Bl[m * 65 + p] * Gl[jl * MM_ + m];
      H[p * NN_ + j0 + jl] = acc;
    }
  }
}

// ---------------------------------------------------------------------------
// k_cg (v8 = R11 + 10 iters + kC folded away):
//  Prologue: zeta = parms@H -> zL; t -> Wl; rhs = Qn^T t - zeta@QfQn
//  - parms@WfQn   (identity: parms@W2 == zeta@QfQn + parms@WfQn, so the
//  W2 precompute kernel is deleted). CG loop: R11 bit-identical.
// ---------------------------------------------------------------------------
__global__ __launch_bounds__(512, 2) void k_cg(
    const float* __restrict__ x, const float* __restrict__ Qn,
    const float* __restrict__ C, const float* __restrict__ parms,
    const float* __restrict__ H, const float* __restrict__ QfQn,
    const float* __restrict__ WfQn, float* __restrict__ out)
{
  const int tid = threadIdx.x;
  const int nA = tid & 255, g2 = tid >> 8;       // role A: batches 2g2, 2g2+1
  const int rB = tid & 127, h = tid >> 7;        // role B: batch h
  const int wid = tid >> 6, lane = tid & 63;
  const int bg0 = blockIdx.x * 4;

  __shared__ __align__(16) float Qs[NN_ * QSTRIDE];
  __shared__ __align__(16) float Pl[4][KKc];
  __shared__ __align__(16) float Wl[4][WLDIM];
  __shared__ __align__(16) float zL[4][NN_];
  __shared__ float red[16];

  // ---- stage Qn -> LDS [256][132] with b128 writes ----
  for (int j = 0; j < 16; ++j) {
    int f4 = j * 512 + tid;
    int n = f4 >> 5, g = f4 & 31;
    float4 v = reinterpret_cast<const float4*>(Qn)[f4];
    *reinterpret_cast<float4*>(&Qs[n * QSTRIDE + 4 * g]) = v;
  }

  // ---- hoist C row rB: (C.p)[rB] = row(rB) . p ----
  float4 creg[32];
#pragma unroll
  for (int j = 0; j < 32; ++j)
    creg[j] = reinterpret_cast<const float4*>(C)[rB * 32 + j];

  // ---- role-A constants ----
  const int b0A = bg0 + 2 * g2, b1A = b0A + 1;
  float xa0 = x[b0A * NN_ + nA];
  float xa1 = x[b1A * NN_ + nA];
  const float dA0 = 1.f + xa0 * xa0;
  const float dA1 = 1.f + xa1 * xa1;
  const int nAp = nA + 4 * (nA >> 6);            // padded Wl index for row nA

  // ---- role-B quad-axpy constants ----
  const int cbase = rB & 64;                     // wave's 64-col base
  const int cg = lane & 15, rc = lane >> 4;
  const int n0q = rc * 64;                       // this lane's row chunk
  const int wbase = 68 * rc;                     // padded Wl chunk base
  const int srcl = (lane & 48) | (lane >> 2);    // redistribution source lane
  const int e = lane & 3;                        // component select

  // ================= PROLOGUE (fused k_vec, W2 folded away) =================
  // role A: zeta, t for 2 batches at row nA
  {
    float za0 = 0.f, za1 = 0.f;
    for (int p = 0; p < PP_; ++p) {
      float hv = H[p * NN_ + nA];                // coalesced; parms wave-uniform
      za0 += parms[b0A * PP_ + p] * hv;
      za1 += parms[b1A * PP_ + p] * hv;
    }
    zL[2 * g2][nA] = za0;
    zL[2 * g2 + 1][nA] = za1;
    Wl[2 * g2][nAp] = dA0 * (xa0 - za0);         // t
    Wl[2 * g2 + 1][nAp] = dA1 * (xa1 - za1);
  }
  __syncthreads();

  // role B: rhs[rB] = (Qn^T t)[rB] - (zeta@QfQn)[rB] - (parms@WfQn)[rB]
  float rr;
  {
    float4 v4 = {0.f, 0.f, 0.f, 0.f};
#pragma unroll 4
    for (int j4 = 0; j4 < 16; ++j4) {
      float4 w4 = *reinterpret_cast<const float4*>(&Wl[h][wbase + 4 * j4]);
      int n = n0q + 4 * j4;
      float4 q0 = *reinterpret_cast<const float4*>(&Qs[(n + 0) * QSTRIDE + cbase + 4 * cg]);
      float4 q1 = *reinterpret_cast<const float4*>(&Qs[(n + 1) * QSTRIDE + cbase + 4 * cg]);
      float4 q2 = *reinterpret_cast<const float4*>(&Qs[(n + 2) * QSTRIDE + cbase + 4 * cg]);
      float4 q3 = *reinterpret_cast<const float4*>(&Qs[(n + 3) * QSTRIDE + cbase + 4 * cg]);
      v4.x += w4.x * q0.x + w4.y * q1.x + w4.z * q2.x + w4.w * q3.x;
      v4.y += w4.x * q0.y + w4.y * q1.y + w4.z * q2.y + w4.w * q3.y;
      v4.z += w4.x * q0.z + w4.y * q1.z + w4.z * q2.z + w4.w * q3.z;
      v4.w += w4.x * q0.w + w4.y * q1.w + w4.z * q2.w + w4.w * q3.w;
    }
    v4.x += __shfl_xor(v4.x, 16, 64); v4.y += __shfl_xor(v4.y, 16, 64);
    v4.z += __shfl_xor(v4.z, 16, 64); v4.w += __shfl_xor(v4.w, 16, 64);
    v4.x += __shfl_xor(v4.x, 32, 64); v4.y += __shfl_xor(v4.y, 32, 64);
    v4.z += __shfl_xor(v4.z, 32, 64); v4.w += __shfl_xor(v4.w, 32, 64);
    float vsx = __shfl(v4.x, srcl, 64), vsy = __shfl(v4.y, srcl, 64);
    float vsz = __shfl(v4.z, srcl, 64), vsw = __shfl(v4.w, srcl, 64);
    rr = (e == 0) ? vsx : (e == 1) ? vsy : (e == 2) ? vsz : vsw;
    // - zeta @ QfQn  (zL broadcast, QfQn coalesced from L2)
    for (int n = 0; n < NN_; ++n)
      rr -= zL[h][n] * QfQn[n * KKc + rB];
    // - parms @ WfQn
    for (int p = 0; p < PP_; ++p)
      rr -= parms[(bg0 + h) * PP_ + p] * WfQn[p * KKc + rB];
  }

  // ---- CG init ----
  float p = rr, z = 0.f;
  Pl[h][rB] = p;
  float t0r = rr * rr;
#pragma unroll
  for (int m = 32; m; m >>= 1) t0r += __shfl_xor(t0r, m, 64);
  if (lane == 0) red[wid] = t0r;
  __syncthreads();
  float rs = red[2 * h] + red[2 * h + 1];

  const float4* PlA0 = reinterpret_cast<const float4*>(Pl[2 * g2]);
  const float4* PlA1 = reinterpret_cast<const float4*>(Pl[2 * g2 + 1]);
  const float4* PlB  = reinterpret_cast<const float4*>(Pl[h]);

  for (int it = 0; it < CG_ITERS; ++it) {
    // ---- role A: u = Qn p (b128 row reads + float4 P broadcast) ----
    float u0 = 0.f, u1 = 0.f;
#pragma unroll 8
    for (int gp = 0; gp < 32; ++gp) {
      float4 q = *reinterpret_cast<const float4*>(&Qs[nA * QSTRIDE + 4 * gp]);
      float4 pa = PlA0[gp];
      float4 pb = PlA1[gp];
      u0 += q.x * pa.x + q.y * pa.y + q.z * pa.z + q.w * pa.w;
      u1 += q.x * pb.x + q.y * pb.y + q.z * pb.z + q.w * pb.w;
    }
    Wl[2 * g2][nAp] = dA0 * u0;
    Wl[2 * g2 + 1][nAp] = dA1 * u1;
    __syncthreads();                             // bar 1: W ready

    // ---- role B: v = QnT W via quad-axpy (b128 Qs + b128 Wl) ----
    float4 v4 = {0.f, 0.f, 0.f, 0.f};
#pragma unroll 4
    for (int j4 = 0; j4 < 16; ++j4) {
      float4 w4 = *reinterpret_cast<const float4*>(&Wl[h][wbase + 4 * j4]);
      int n = n0q + 4 * j4;
      float4 q0 = *reinterpret_cast<const float4*>(&Qs[(n + 0) * QSTRIDE + cbase + 4 * cg]);
      float4 q1 = *reinterpret_cast<const float4*>(&Qs[(n + 1) * QSTRIDE + cbase + 4 * cg]);
      float4 q2 = *reinterpret_cast<const float4*>(&Qs[(n + 2) * QSTRIDE + cbase + 4 * cg]);
      float4 q3 = *reinterpret_cast<const float4*>(&Qs[(n + 3) * QSTRIDE + cbase + 4 * cg]);
      v4.x += w4.x * q0.x + w4.y * q1.x + w4.z * q2.x + w4.w * q3.x;
      v4.y += w4.x * q0.y + w4.y * q1.y + w4.z * q2.y + w4.w * q3.y;
      v4.z += w4.x * q0.z + w4.y * q1.z + w4.z * q2.z + w4.w * q3.z;
      v4.w += w4.x * q0.w + w4.y * q1.w + w4.z * q2.w + w4.w * q3.w;
    }
    v4.x += __shfl_xor(v4.x, 16, 64); v4.y += __shfl_xor(v4.y, 16, 64);
    v4.z += __shfl_xor(v4.z, 16, 64); v4.w += __shfl_xor(v4.w, 16, 64);
    v4.x += __shfl_xor(v4.x, 32, 64); v4.y += __shfl_xor(v4.y, 32, 64);
    v4.z += __shfl_xor(v4.z, 32, 64); v4.w += __shfl_xor(v4.w, 32, 64);
    float vsx = __shfl(v4.x, srcl, 64), vsy = __shfl(v4.y, srcl, 64);
    float vsz = __shfl(v4.z, srcl, 64), vsw = __shfl(v4.w, srcl, 64);
    float v = (e == 0) ? vsx : (e == 1) ? vsy : (e == 2) ? vsz : vsw;

    // ---- + C p (creg) ----
#pragma unroll
    for (int j = 0; j < 32; ++j) {
      float4 p4 = PlB[j];
      float4 c4 = creg[j];
      v += c4.x * p4.x + c4.y * p4.y + c4.z * p4.z + c4.w * p4.w;
    }

    // ---- pv reduction ----
    float pv = p * v;
#pragma unroll
    for (int m = 32; m; m >>= 1) pv += __shfl_xor(pv, m, 64);
    if (lane == 0) red[wid] = pv;
    __syncthreads();                             // bar 2
    float pvb = red[2 * h] + red[2 * h + 1];
    float alpha = rs / (pvb + 1e-30f);
    z += alpha * p;
    rr -= alpha * v;

    // ---- rs_new = r.r (direct reduction) ----
    float rn = rr * rr;
#pragma unroll
    for (int m = 32; m; m >>= 1) rn += __shfl_xor(rn, m, 64);
    if (lane == 0) red[8 + wid] = rn;
    __syncthreads();                             // bar 3
    float rsn = red[8 + 2 * h] + red[8 + 2 * h + 1];
    float beta = rsn / (rs + 1e-30f);
    rs = rsn;
    p = rr + beta * p;
    Pl[h][rB] = p;
    __syncthreads();                             // bar 4: P ready
  }

  // ---- epilogue: Pl <- z ; out = zL + Qn z (single write) ----
  Pl[h][rB] = z;
  __syncthreads();
  float o0 = zL[2 * g2][nA], o1 = zL[2 * g2 + 1][nA];
#pragma unroll 8
  for (int gp = 0; gp < 32; ++gp) {
    float4 q = *reinterpret_cast<const float4*>(&Qs[nA * QSTRIDE + 4 * gp]);
    float4 za = PlA0[gp];
    float4 zb = PlA1[gp];
    o0 += q.x * za.x + q.y * za.y + q.z * za.z + q.w * za.w;
    o1 += q.x * zb.x + q.y * zb.y + q.z * zb.z + q.w * zb.w;
  }
  out[b0A * NN_ + nA] = o0;
  out[b1A * NN_ + nA] = o1;
}

// ---------------------------------------------------------------------------
extern "C" void kernel_launch(void* const* d_in, const int* in_sizes, int n_in,
                              void* d_out, int out_size, void* d_ws, size_t ws_size,
                              hipStream_t stream)
{
  const float* x     = (const float*)d_in[0];
  const float* parms = (const float*)d_in[1];
  // d_in[2] = A : unused (cancels algebraically)
  const float* Bp    = (const float*)d_in[3];
  const float* Qf    = (const float*)d_in[4];
  const float* Wf    = (const float*)d_in[5];
  const float* Qr    = (const float*)d_in[6];
  const float* Qn    = (const float*)d_in[7];
  const float* Rr    = (const float*)d_in[8];

  // Workspace: 106,496 floats = 0.41 MB (proven-safe region).
  float* ws   = (float*)d_ws;
  float* QfQn = ws;                 // [0      , 32768)
  float* WfQn = QfQn + 32768;       // [32768  , 40960)
  float* GT   = WfQn + 8192;        // [40960  , 73728)   GT[j][m] (256x128)
  float* H    = GT + 32768;         // [73728  , 90112)   H[p][n]  (64x256)
  float* Cm   = H + 16384;          // [90112  , 106496)  C (128x128)

  float* outp = (float*)d_out;

  hipLaunchKernelGGL(kA, dim3(224), dim3(256), 0, stream,
                     Qf, Qn, Wf, Qr, Rr, QfQn, WfQn, GT);
  hipLaunchKernelGGL(kB, dim3(80), dim3(256), 0, stream,
                     Qn, QfQn, Bp, GT, Cm, H);
  hipLaunchKernelGGL(k_cg, dim3(256), dim3(512), 0, stream,
                     x, Qn, Cm, parms, H, QfQn, WfQn, outp);
}